// Round 9
// baseline (267.108 us; speedup 1.0000x reference)
//
#include <hip/hip_runtime.h>

// Causal MHA. B=4, S=2048, V=1024, H=16, hs=64. Output fp32.
// R18: un-paired attn blocks — one 64-row strip per block, 2048 blocks
// (was 1024 paired; grid was the binding constraint at 4 blocks/CU with
// all pipes <30%). LDS 27.6KB -> 5 resident blocks/CU. LPT: qb=(31-x)*64
// so longest blocks dispatch first, short ones backfill. Each wave owns
// ONE 16-row subtile (no u-loop, oacc 16 VGPR). Fixed-reference softmax
// (R17: p=exp2(s), no max tracking) makes strips fully independent.
// qkv/oproj/wcvt/detect unchanged from R17.
#define B_  4
#define S_  2048
#define V_  1024
#define H_  16
#define HS_ 64
#define GK_ 1024
#define GN_ 1024

typedef unsigned short u16;
typedef __bf16 bf16x8 __attribute__((ext_vector_type(8)));
typedef float  f32x4  __attribute__((ext_vector_type(4)));

__device__ __forceinline__ float bf2f(u16 u) {
  return __uint_as_float(((unsigned int)u) << 16);
}
__device__ __forceinline__ float lo16(unsigned int w) { return __uint_as_float(w << 16); }
__device__ __forceinline__ float hi16(unsigned int w) { return __uint_as_float(w & 0xffff0000u); }
__device__ __forceinline__ u16 f2bf(float f) {
  unsigned int u = __float_as_uint(f);
  unsigned int r = u + 0x7fffu + ((u >> 16) & 1u);  // RNE
  return (u16)(r >> 16);
}
__device__ __forceinline__ unsigned int cvtpk(float lo, float hi) {
  unsigned int r;
  asm("v_cvt_pk_bf16_f32 %0, %1, %2" : "=v"(r) : "v"(lo), "v"(hi));
  return r;
}

// ---------------------------------------------------------------------------
// Input-storage detector (fp32 vs bf16; see R5/R7 notes).
// ---------------------------------------------------------------------------
__global__ __launch_bounds__(256) void detect_kernel(
    const unsigned int* __restrict__ x32, int* __restrict__ flag)
{
  __shared__ int zred[256];
  __shared__ int nred[256];
  const int tid = threadIdx.x;
  int nz = 0, nn = 0;
  for (int i = tid; i < 16384; i += 256) {
    unsigned int lo = x32[i] & 0xffffu;
    if (lo == 0u) nz++;
    if ((lo & 0x7f80u) == 0x7f80u && (lo & 0x7fu) != 0u) nn++;
  }
  zred[tid] = nz; nred[tid] = nn;
  __syncthreads();
  for (int s = 128; s > 0; s >>= 1) {
    if (tid < s) { zred[tid] += zred[tid + s]; nred[tid] += nred[tid + s]; }
    __syncthreads();
  }
  if (tid == 0) *flag = (zred[0] > 8192 || nred[0] > 0) ? 1 : 0;
}

// ---------------------------------------------------------------------------
// W_out -> bf16 (into q's dead workspace region, full mode only).
// ---------------------------------------------------------------------------
__global__ __launch_bounds__(256) void wcvt_kernel(
    const void* __restrict__ w, u16* __restrict__ wb, const int* __restrict__ flag)
{
  const int i = (blockIdx.x * 256 + threadIdx.x) * 4;
  if (*flag) {
    float4 f = *(const float4*)((const float*)w + i);
    unsigned int p0 = (unsigned int)f2bf(f.x) | ((unsigned int)f2bf(f.y) << 16);
    unsigned int p1 = (unsigned int)f2bf(f.z) | ((unsigned int)f2bf(f.w) << 16);
    *(uint2*)(wb + i) = make_uint2(p0, p1);
  } else {
    *(uint2*)(wb + i) = *(const uint2*)((const u16*)w + i);
  }
}

// ---------------------------------------------------------------------------
// MFMA QKV projection. C[m][e] = sum_d A[m][d] * W[e][d]. (R17)
// ---------------------------------------------------------------------------
__global__ __launch_bounds__(256) void qkv_mfma_kernel(
    const void* __restrict__ x, const void* __restrict__ wqkv,
    u16* __restrict__ q, u16* __restrict__ k, u16* __restrict__ v,
    const int* __restrict__ flag)
{
  __shared__ __align__(16) u16 Ws[192 * 80];   // 30720 B
  const int tid = threadIdx.x;
  const int isf32 = *flag;
  for (int idx = tid; idx < 192 * 4; idx += 256) {
    const int row = idx >> 2, c0 = (idx & 3) * 16;
    u16 t16[16];
    if (isf32) {
      const float4* gp = (const float4*)((const float*)wqkv + row * 64 + c0);
      float4 f0 = gp[0], f1 = gp[1], f2 = gp[2], f3 = gp[3];
      t16[0]=f2bf(f0.x); t16[1]=f2bf(f0.y); t16[2]=f2bf(f0.z); t16[3]=f2bf(f0.w);
      t16[4]=f2bf(f1.x); t16[5]=f2bf(f1.y); t16[6]=f2bf(f1.z); t16[7]=f2bf(f1.w);
      t16[8]=f2bf(f2.x); t16[9]=f2bf(f2.y); t16[10]=f2bf(f2.z); t16[11]=f2bf(f2.w);
      t16[12]=f2bf(f3.x); t16[13]=f2bf(f3.y); t16[14]=f2bf(f3.z); t16[15]=f2bf(f3.w);
    } else {
      const u16* gp = (const u16*)wqkv + row * 64 + c0;
      *(uint4*)t16 = *(const uint4*)gp;
      *(uint4*)(t16 + 8) = *(const uint4*)(gp + 8);
    }
    *(uint4*)(Ws + row * 80 + c0) = *(uint4*)t16;
    *(uint4*)(Ws + row * 80 + c0 + 8) = *(uint4*)(t16 + 8);
  }
  __syncthreads();

  const int m0 = blockIdx.x * 128;
  const int w = tid >> 6, lane = tid & 63;
  const int ar = lane & 15, quad = lane >> 4;
  const int rbase = m0 + (w & 1) * 64;     // wave rows (4 row-tiles)
  const int cbase = (w >> 1) * 96;         // wave cols (6 col-tiles)

  // A fragments direct from global: [m=ar][k=ks*32+quad*8+j]
  bf16x8 af[4][2];
#pragma unroll
  for (int rt = 0; rt < 4; ++rt) {
    const size_t row = (size_t)(rbase + rt * 16 + ar) * 64;
    if (isf32) {
      const float* gp = (const float*)x + row;
#pragma unroll
      for (int ks = 0; ks < 2; ++ks) {
        const float4* g4 = (const float4*)(gp + ks * 32 + quad * 8);
        float4 f0 = g4[0], f1 = g4[1];
        u16 t8[8];
        t8[0]=f2bf(f0.x); t8[1]=f2bf(f0.y); t8[2]=f2bf(f0.z); t8[3]=f2bf(f0.w);
        t8[4]=f2bf(f1.x); t8[5]=f2bf(f1.y); t8[6]=f2bf(f1.z); t8[7]=f2bf(f1.w);
        af[rt][ks] = *(bf16x8*)t8;
      }
    } else {
      const u16* gp = (const u16*)x + row;
#pragma unroll
      for (int ks = 0; ks < 2; ++ks)
        af[rt][ks] = *(const bf16x8*)(gp + ks * 32 + quad * 8);
    }
  }

  f32x4 acc[4][6] = {};
#pragma unroll
  for (int ks = 0; ks < 2; ++ks)
#pragma unroll
    for (int t = 0; t < 6; ++t) {
      const bf16x8 bfr = *(const bf16x8*)(Ws + (cbase + t * 16 + ar) * 80 + ks * 32 + quad * 8);
#pragma unroll
      for (int rt = 0; rt < 4; ++rt)
        acc[rt][t] = __builtin_amdgcn_mfma_f32_16x16x32_bf16(af[rt][ks], bfr, acc[rt][t], 0, 0, 0);
    }

  // epilogue: m -> (z, s, h); e -> (matrix, d)
#pragma unroll
  for (int rt = 0; rt < 4; ++rt)
#pragma unroll
    for (int r = 0; r < 4; ++r) {
      const int m = rbase + rt * 16 + quad * 4 + r;
      const int z = m >> 15, s = (m >> 4) & (S_ - 1), h = m & (H_ - 1);
      const size_t base = (((size_t)z * H_ + h) * S_ + s) * HS_;
#pragma unroll
      for (int t = 0; t < 6; ++t) {
        const int e = cbase + t * 16 + ar;
        u16* dst = (e < 64) ? q : (e < 128) ? k : v;
        dst[base + (e & 63)] = f2bf(acc[rt][t][r]);
      }
    }
}

// ---------------------------------------------------------------------------
// Fallback vector QKV (per-batch mode only; unchanged from R9).
// ---------------------------------------------------------------------------
__global__ __launch_bounds__(256) void qkv_kernel(
    const void* __restrict__ x, int b0, const void* __restrict__ w,
    u16* __restrict__ q, u16* __restrict__ k, u16* __restrict__ v,
    const int* __restrict__ flag)
{
  __shared__ __align__(16) float Ws[192 * 64];
  const int tid = threadIdx.x;
  const int isf32 = *flag;
  if (isf32) {
    for (int i = tid; i < 192 * 64; i += 256) Ws[i] = ((const float*)w)[i];
  } else {
    for (int i = tid; i < 192 * 64; i += 256) Ws[i] = bf2f(((const u16*)w)[i]);
  }
  __syncthreads();

  const int th = blockIdx.x * 256 + tid;
  const int h = th & (H_ - 1);
  const int s = th >> 4;
  const int b = b0 + blockIdx.z;
  const size_t zoff = (size_t)blockIdx.z * H_ * S_ * HS_;
  const size_t xoff = ((size_t)b * S_ + s) * V_ + h * HS_;

  float xf[64];
  if (isf32) {
    const float4* xp = (const float4*)((const float*)x + xoff);
#pragma unroll
    for (int i = 0; i < 16; ++i) {
      float4 u = xp[i];
      xf[4*i+0] = u.x; xf[4*i+1] = u.y; xf[4*i+2] = u.z; xf[4*i+3] = u.w;
    }
  } else {
    const uint4* xp = (const uint4*)((const u16*)x + xoff);
#pragma unroll
    for (int i = 0; i < 8; ++i) {
      uint4 u = xp[i];
      xf[8*i+0] = lo16(u.x); xf[8*i+1] = hi16(u.x);
      xf[8*i+2] = lo16(u.y); xf[8*i+3] = hi16(u.y);
      xf[8*i+4] = lo16(u.z); xf[8*i+5] = hi16(u.z);
      xf[8*i+6] = lo16(u.w); xf[8*i+7] = hi16(u.w);
    }
  }

  const size_t obase = zoff + ((size_t)h * S_ + s) * HS_;
#pragma unroll 1
  for (int eg = 0; eg < 12; ++eg) {
    float acc[16];
#pragma unroll
    for (int ee = 0; ee < 16; ++ee) {
      const float4* wr = (const float4*)&Ws[(eg * 16 + ee) * 64];
      float a = 0.f;
#pragma unroll
      for (int d4 = 0; d4 < 16; ++d4) {
        float4 wv = wr[d4];
        a += xf[d4*4+0]*wv.x + xf[d4*4+1]*wv.y + xf[d4*4+2]*wv.z + xf[d4*4+3]*wv.w;
      }
      acc[ee] = a;
    }
    u16* dst = (eg < 4) ? q : (eg < 8) ? k : v;
    const int d0 = (eg & 3) * 16;
    unsigned int p[8];
#pragma unroll
    for (int t = 0; t < 8; ++t)
      p[t] = (unsigned int)f2bf(acc[2*t]) | ((unsigned int)f2bf(acc[2*t+1]) << 16);
    uint4* dp = (uint4*)(dst + obase + d0);
    dp[0] = make_uint4(p[0], p[1], p[2], p[3]);
    dp[1] = make_uint4(p[4], p[5], p[6], p[7]);
  }
}

// ---------------------------------------------------------------------------
// R18 MFMA flash attention. One 64-row strip per block (2048 blocks, LPT:
// qb = (31-x)*64 so big blocks first). 4 waves; wave w owns rows
// [qb+w*16, qb+w*16+16). Swapped QK^T D[k=quad*4+r][q=col]; fixed-reference
// softmax p=exp2(s) (R17); P via cvt_pk; l partials reduced in epilogue.
// ---------------------------------------------------------------------------
__global__ __launch_bounds__(256, 4) void attn_mfma_kernel(
    const u16* __restrict__ q, const u16* __restrict__ k,
    const u16* __restrict__ v, u16* __restrict__ o)
{
  const int z   = blockIdx.z;
  const int h   = blockIdx.y;
  const int qb  = (31 - blockIdx.x) * 64;  // LPT: longest first
  const int tid = threadIdx.x;
  const int w = tid >> 6, lane = tid & 63;
  const int col = lane & 15, quad = lane >> 4;
  const int ru = qb + w * 16;

  __shared__ __align__(16) u16 Ks[64 * 72];
  __shared__ __align__(16) u16 Vt[64 * 72];
  __shared__ __align__(16) u16 Ps[4][16 * 72];

  const size_t hs = ((size_t)z * H_ + h) * S_ * HS_;

  // Q fragment; scale folds 1/8 and log2(e).
  const float qs = 0.125f * 1.44269504089f;
  bf16x8 qf[2];
  {
    const u16* qp = q + hs + (size_t)(ru + col) * HS_ + quad * 8;
#pragma unroll
    for (int ks = 0; ks < 2; ++ks) {
      u16 t8[8];
      *(uint4*)t8 = *(const uint4*)(qp + ks * 32);
#pragma unroll
      for (int e = 0; e < 8; ++e) t8[e] = f2bf(bf2f(t8[e]) * qs);
      qf[ks] = *(bf16x8*)t8;
    }
  }

  const int sr = tid >> 2, sc = (tid & 3) * 16;        // K staging: 64x64
  const int vr = (tid & 31) * 2, vc = (tid >> 5) * 8;  // V staging: 2 rows x 8 cols

  f32x4 oacc[4] = {};
  float l_run = 0.f;                   // per-lane PARTIAL row sum

  // prologue: load tile 0
  uint4 k0, k1, va, vb;
  {
    const u16* kp = k + hs + (size_t)sr * HS_ + sc;
    k0 = *(const uint4*)kp;
    k1 = *(const uint4*)(kp + 8);
    const u16* vp = v + hs + (size_t)vr * HS_ + vc;
    va = *(const uint4*)vp;
    vb = *(const uint4*)(vp + HS_);
  }

  for (int jb = 0; jb <= qb; jb += 64) {
    __syncthreads();                       // all waves done reading prev tile
    *(uint4*)(Ks + sr * 72 + sc)     = k0;
    *(uint4*)(Ks + sr * 72 + sc + 8) = k1;
    {
      const u16* pa = (const u16*)&va;
      const u16* pb = (const u16*)&vb;
#pragma unroll
      for (int e = 0; e < 8; ++e)
        *(unsigned int*)(Vt + (vc + e) * 72 + vr) =
            (unsigned int)pa[e] | ((unsigned int)pb[e] << 16);
    }
    __syncthreads();

    if (jb < qb) {                         // prefetch next tile under compute
      const u16* kp = k + hs + (size_t)(jb + 64 + sr) * HS_ + sc;
      k0 = *(const uint4*)kp;
      k1 = *(const uint4*)(kp + 8);
      const u16* vp = v + hs + (size_t)(jb + 64 + vr) * HS_ + vc;
      va = *(const uint4*)vp;
      vb = *(const uint4*)(vp + HS_);
    }

    // Swapped QK^T: D[k-row = quad*4+r][q-col = col]
    f32x4 sacc[4] = {};
    __builtin_amdgcn_s_setprio(1);
#pragma unroll
    for (int ks = 0; ks < 2; ++ks)
#pragma unroll
      for (int t = 0; t < 4; ++t) {
        const bf16x8 kf = *(const bf16x8*)(Ks + (t * 16 + col) * 72 + ks * 32 + quad * 8);
        sacc[t] = __builtin_amdgcn_mfma_f32_16x16x32_bf16(kf, qf[ks], sacc[t], 0, 0, 0);
      }
    __builtin_amdgcn_s_setprio(0);

    if (jb == qb) {                        // final tile: mask k > q
      const int q_l = ru + col;
#pragma unroll
      for (int t = 0; t < 4; ++t) {
        const int kb = jb + t * 16 + quad * 4;
#pragma unroll
        for (int r = 0; r < 4; ++r)
          if (kb + r > q_l) sacc[t][r] = -INFINITY;
      }
    }

    // Fixed-reference softmax: p = exp2(s) directly (|s| <~ 16; safe).
    float ls = 0.f;
#pragma unroll
    for (int t = 0; t < 4; ++t) {
      const float p0 = __builtin_amdgcn_exp2f(sacc[t][0]);
      const float p1 = __builtin_amdgcn_exp2f(sacc[t][1]);
      const float p2 = __builtin_amdgcn_exp2f(sacc[t][2]);
      const float p3 = __builtin_amdgcn_exp2f(sacc[t][3]);
      ls += (p0 + p1) + (p2 + p3);
      *(uint2*)(Ps[w] + col * 72 + t * 16 + quad * 4) =
          make_uint2(cvtpk(p0, p1), cvtpk(p2, p3));
    }
    l_run += ls;

    __builtin_amdgcn_s_setprio(1);
#pragma unroll
    for (int ks = 0; ks < 2; ++ks) {
      const bf16x8 pf = *(const bf16x8*)(Ps[w] + col * 72 + ks * 32 + quad * 8);
#pragma unroll
      for (int nt = 0; nt < 4; ++nt) {
        const bf16x8 vf = *(const bf16x8*)(Vt + (nt * 16 + col) * 72 + ks * 32 + quad * 8);
        oacc[nt] = __builtin_amdgcn_mfma_f32_16x16x32_bf16(pf, vf, oacc[nt], 0, 0, 0);
      }
    }
    __builtin_amdgcn_s_setprio(0);
  }

  u16* ob = o + (size_t)z * S_ * V_ + h * HS_;
  float lt = l_run;                        // reduce partials once
  lt += __shfl_xor(lt, 16);
  lt += __shfl_xor(lt, 32);
  float inv[4];
#pragma unroll
  for (int r = 0; r < 4; ++r) inv[r] = 1.0f / __shfl(lt, quad * 4 + r);
#pragma unroll
  for (int nt = 0; nt < 4; ++nt)
#pragma unroll
    for (int r = 0; r < 4; ++r)
      ob[(size_t)(ru + quad * 4 + r) * V_ + nt * 16 + col] = f2bf(oacc[nt][r] * inv[r]);
}

// ---------------------------------------------------------------------------
// Output projection, MFMA NT-GEMM (R16 reg-prefetch). 128x128 tile, BK=32.
// ---------------------------------------------------------------------------
__global__ __launch_bounds__(256) void oproj_mfma_kernel(
    const u16* __restrict__ a, const u16* __restrict__ bw, float* __restrict__ c)
{
  __shared__ __align__(16) u16 As[128 * 40];
  __shared__ __align__(16) u16 Bs[128 * 40];
  const int tid = threadIdx.x;
  const int m0 = blockIdx.x * 128;
  const int n0 = blockIdx.y * 128;
  const int w = tid >> 6, lane = tid & 63;
  const int col = lane & 15, quad = lane >> 4;
  const int qr = (w & 1) * 64;
  const int qc = (w >> 1) * 64;

  f32x4 acc[4][4] = {};

  const int sr = tid >> 2;
  const int sk = (tid & 3) * 8;
  const u16* ga = a  + (size_t)(m0 + sr) * GK_ + sk;
  const u16* gb = bw + (size_t)(n0 + sr) * GK_ + sk;

  // prologue: stage k0 = 0
  uint4 a0 = *(const uint4*)(ga);
  uint4 a1 = *(const uint4*)(ga + (size_t)64 * GK_);
  uint4 b0 = *(const uint4*)(gb);
  uint4 b1 = *(const uint4*)(gb + (size_t)64 * GK_);

  for (int k0 = 0; k0 < GK_; k0 += 32) {
    __syncthreads();                       // prev tile reads done
    *(uint4*)(As + sr * 40 + sk)        = a0;
    *(uint4*)(As + (64 + sr) * 40 + sk) = a1;
    *(uint4*)(Bs + sr * 40 + sk)        = b0;
    *(uint4*)(Bs + (64 + sr) * 40 + sk) = b1;
    __syncthreads();

    if (k0 + 32 < GK_) {                   // prefetch k+32 under compute
      a0 = *(const uint4*)(ga + k0 + 32);
      a1 = *(const uint4*)(ga + (size_t)64 * GK_ + k0 + 32);
      b0 = *(const uint4*)(gb + k0 + 32);
      b1 = *(const uint4*)(gb + (size_t)64 * GK_ + k0 + 32);
    }

    bf16x8 af[4], bfr[4];
#pragma unroll
    for (int i = 0; i < 4; ++i) {
      af[i]  = *(const bf16x8*)(As + (qr + i * 16 + col) * 40 + quad * 8);
      bfr[i] = *(const bf16x8*)(Bs + (qc + i * 16 + col) * 40 + quad * 8);
    }
    __builtin_amdgcn_s_setprio(1);
#pragma unroll
    for (int i = 0; i < 4; ++i)
#pragma unroll
      for (int j = 0; j < 4; ++j)
        acc[i][j] = __builtin_amdgcn_mfma_f32_16x16x32_bf16(af[i], bfr[j], acc[i][j], 0, 0, 0);
    __builtin_amdgcn_s_setprio(0);
  }

#pragma unroll
  for (int i = 0; i < 4; ++i)
#pragma unroll
    for (int j = 0; j < 4; ++j)
#pragma unroll
      for (int r = 0; r < 4; ++r)
        c[(size_t)(m0 + qr + i * 16 + quad * 4 + r) * GN_ + n0 + qc + j * 16 + col]
            = acc[i][j][r];
}

// ---------------------------------------------------------------------------
// Fallback vector oproj (per-batch mode only; unchanged).
// ---------------------------------------------------------------------------
__global__ __launch_bounds__(256) void oproj_vec_kernel(
    const u16* __restrict__ o, const void* __restrict__ w,
    float* __restrict__ out, const int* __restrict__ flag)
{
  __shared__ __align__(16) float At[64 * 68];
  __shared__ __align__(16) float Wt[64 * 68];
  const int tid = threadIdx.x;
  const size_t zo = (size_t)blockIdx.z * S_ * V_;
  const int m0 = blockIdx.x * 64;
  const int n0 = blockIdx.y * 64;
  const int tr = tid >> 4, tc = tid & 15;
  const int isf32 = *flag;
  const int srow = tid >> 2, sc = (tid & 3) * 16;

  float acc[4][4] = {};

  for (int k0 = 0; k0 < GK_; k0 += 64) {
    float av[16], wv[16];
    {
      const u16* gp = o + zo + (size_t)(m0 + srow) * GK_ + k0 + sc;
      uint4 u0 = *(const uint4*)gp;
      uint4 u1 = *(const uint4*)(gp + 8);
      av[0]=lo16(u0.x); av[1]=hi16(u0.x); av[2]=lo16(u0.y); av[3]=hi16(u0.y);
      av[4]=lo16(u0.z); av[5]=hi16(u0.z); av[6]=lo16(u0.w); av[7]=hi16(u0.w);
      av[8]=lo16(u1.x); av[9]=hi16(u1.x); av[10]=lo16(u1.y); av[11]=hi16(u1.y);
      av[12]=lo16(u1.z); av[13]=hi16(u1.z); av[14]=lo16(u1.w); av[15]=hi16(u1.w);
    }
    if (isf32) {
      const float4* gp = (const float4*)((const float*)w + (size_t)(n0 + srow) * GK_ + k0 + sc);
#pragma unroll
      for (int i = 0; i < 4; ++i) {
        float4 f = gp[i];
        wv[4*i+0]=f.x; wv[4*i+1]=f.y; wv[4*i+2]=f.z; wv[4*i+3]=f.w;
      }
    } else {
      const u16* gp = (const u16*)w + (size_t)(n0 + srow) * GK_ + k0 + sc;
      uint4 u0 = *(const uint4*)gp;
      uint4 u1 = *(const uint4*)(gp + 8);
      wv[0]=lo16(u0.x); wv[1]=hi16(u0.x); wv[2]=lo16(u0.y); wv[3]=hi16(u0.y);
      wv[4]=lo16(u0.z); wv[5]=hi16(u0.z); wv[6]=lo16(u0.w); wv[7]=hi16(u0.w);
      wv[8]=lo16(u1.x); wv[9]=hi16(u1.x); wv[10]=lo16(u1.y); wv[11]=hi16(u1.y);
      wv[12]=lo16(u1.z); wv[13]=hi16(u1.z); wv[14]=lo16(u1.w); wv[15]=hi16(u1.w);
    }
    __syncthreads();
#pragma unroll
    for (int i = 0; i < 16; ++i) {
      At[(sc + i) * 68 + srow] = av[i];
      Wt[(sc + i) * 68 + srow] = wv[i];
    }
    __syncthreads();

#pragma unroll 4
    for (int kk = 0; kk < 64; ++kk) {
      float4 a4 = *(const float4*)&At[kk * 68 + tr * 4];
      float4 w4 = *(const float4*)&Wt[kk * 68 + tc * 4];
      acc[0][0] += a4.x*w4.x; acc[0][1] += a4.x*w4.y; acc[0][2] += a4.x*w4.z; acc[0][3] += a4.x*w4.w;
      acc[1][0] += a4.y*w4.x; acc[1][1] += a4.y*w4.y; acc[1][2] += a4.y*w4.z; acc[1][3] += a4.y*w4.w;
      acc[2][0] += a4.z*w4.x; acc[2][1] += a4.z*w4.y; acc[2][2] += a4.z*w4.z; acc[2][3] += a4.z*w4.w;
      acc[3][0] += a4.w*w4.x; acc[3][1] += a4.w*w4.y; acc[3][2] += a4.w*w4.z; acc[3][3] += a4.w*w4.w;
    }
  }

#pragma unroll
  for (int r = 0; r < 4; ++r) {
    const int row = m0 + tr * 4 + r;
    *(float4*)(out + zo + (size_t)row * GN_ + n0 + tc * 4) =
        make_float4(acc[r][0], acc[r][1], acc[r][2], acc[r][3]);
  }
}

// ---------------------------------------------------------------------------
extern "C" void kernel_launch(void* const* d_in, const int* in_sizes, int n_in,
                              void* d_out, int out_size, void* d_ws, size_t ws_size,
                              hipStream_t stream) {
  const void* x = d_in[0];
  const void* wqkv = (n_in > 1) ? d_in[1] : d_in[0];
  const void* wout = (n_in > 2) ? d_in[2] : d_in[0];
  for (int i = 0; i < n_in; ++i) {
    if      (in_sizes[i] == B_ * S_ * V_)  x    = d_in[i];
    else if (in_sizes[i] == 3 * HS_ * HS_) wqkv = d_in[i];
    else if (in_sizes[i] == V_ * V_)       wout = d_in[i];
  }
  float* out = (float*)d_out;

  const size_t per_b = (size_t)H_ * S_ * HS_;
  const size_t SV = (size_t)S_ * V_;
  int* flag = (int*)d_ws;
  const bool full = ws_size >= (16 + 16 * per_b * sizeof(u16));
  const size_t stride = full ? 4 * per_b : per_b;
  u16* q = (u16*)((char*)d_ws + 16);
  u16* k = q + stride;
  u16* v = k + stride;
  u16* o = v + stride;

  detect_kernel<<<dim3(1), dim3(256), 0, stream>>>((const unsigned int*)x, flag);
  if (full) {
    qkv_mfma_kernel<<<dim3((B_ * S_ * H_) / 128), dim3(256), 0, stream>>>(
        x, wqkv, q, k, v, flag);
    attn_mfma_kernel<<<dim3(32, 16, B_), dim3(256), 0, stream>>>(q, k, v, o);
    u16* wb = q;   // q dead after attn
    wcvt_kernel<<<dim3((V_ * V_) / 1024), dim3(256), 0, stream>>>(wout, wb, flag);
    oproj_mfma_kernel<<<dim3((B_ * S_) / 128, GN_ / 128), dim3(256), 0, stream>>>(o, wb, out);
  } else {
    for (int b = 0; b < B_; ++b) {
      qkv_kernel<<<dim3(128, 1, 1), dim3(256), 0, stream>>>(x, b, wqkv, q, k, v, flag);
      attn_mfma_kernel<<<dim3(32, 16, 1), dim3(256), 0, stream>>>(q, k, v, o);
      oproj_vec_kernel<<<dim3(32, 16, 1), dim3(256), 0, stream>>>(
          o, wout, out + (size_t)b * SV, flag);
    }
  }
}

// Round 11
// 245.747 us; speedup vs baseline: 1.0869x; 1.0869x over previous
//
#include <hip/hip_runtime.h>

// Causal MHA. B=4, S=2048, V=1024, H=16, hs=64. Output fp32.
// R19 (resubmit after infra failure): R17 paired kernel (best: 75.6us) +
// K/V LDS DOUBLE-BUFFER with ONE barrier per iteration (was: barrier ->
// vmcnt0+ds_write -> barrier serial bubble every tile; R18 proved this
// fixed per-iteration chain dominates -- more blocks made it WORSE).
// Schedule: issue loads(j+1) | compute buf[c] | write buf[c^1] | barrier.
// Hazard-safe: buf c^1 last read before previous barrier. LDS 46KB ->
// 3 blocks/CU (grid gives 4; measured eff was 2.6). Fixed-ref softmax
// (R17), uniform-work pairing (R13), cvt_pk (R15), oproj reg-prefetch (R16).
#define B_  4
#define S_  2048
#define V_  1024
#define H_  16
#define HS_ 64
#define GK_ 1024
#define GN_ 1024

typedef unsigned short u16;
typedef __bf16 bf16x8 __attribute__((ext_vector_type(8)));
typedef float  f32x4  __attribute__((ext_vector_type(4)));

__device__ __forceinline__ float bf2f(u16 u) {
  return __uint_as_float(((unsigned int)u) << 16);
}
__device__ __forceinline__ float lo16(unsigned int w) { return __uint_as_float(w << 16); }
__device__ __forceinline__ float hi16(unsigned int w) { return __uint_as_float(w & 0xffff0000u); }
__device__ __forceinline__ u16 f2bf(float f) {
  unsigned int u = __float_as_uint(f);
  unsigned int r = u + 0x7fffu + ((u >> 16) & 1u);  // RNE
  return (u16)(r >> 16);
}
__device__ __forceinline__ unsigned int cvtpk(float lo, float hi) {
  unsigned int r;
  asm("v_cvt_pk_bf16_f32 %0, %1, %2" : "=v"(r) : "v"(lo), "v"(hi));
  return r;
}

// ---------------------------------------------------------------------------
// Input-storage detector (fp32 vs bf16; see R5/R7 notes).
// ---------------------------------------------------------------------------
__global__ __launch_bounds__(256) void detect_kernel(
    const unsigned int* __restrict__ x32, int* __restrict__ flag)
{
  __shared__ int zred[256];
  __shared__ int nred[256];
  const int tid = threadIdx.x;
  int nz = 0, nn = 0;
  for (int i = tid; i < 16384; i += 256) {
    unsigned int lo = x32[i] & 0xffffu;
    if (lo == 0u) nz++;
    if ((lo & 0x7f80u) == 0x7f80u && (lo & 0x7fu) != 0u) nn++;
  }
  zred[tid] = nz; nred[tid] = nn;
  __syncthreads();
  for (int s = 128; s > 0; s >>= 1) {
    if (tid < s) { zred[tid] += zred[tid + s]; nred[tid] += nred[tid + s]; }
    __syncthreads();
  }
  if (tid == 0) *flag = (zred[0] > 8192 || nred[0] > 0) ? 1 : 0;
}

// ---------------------------------------------------------------------------
// W_out -> bf16 (into q's dead workspace region, full mode only).
// ---------------------------------------------------------------------------
__global__ __launch_bounds__(256) void wcvt_kernel(
    const void* __restrict__ w, u16* __restrict__ wb, const int* __restrict__ flag)
{
  const int i = (blockIdx.x * 256 + threadIdx.x) * 4;
  if (*flag) {
    float4 f = *(const float4*)((const float*)w + i);
    unsigned int p0 = (unsigned int)f2bf(f.x) | ((unsigned int)f2bf(f.y) << 16);
    unsigned int p1 = (unsigned int)f2bf(f.z) | ((unsigned int)f2bf(f.w) << 16);
    *(uint2*)(wb + i) = make_uint2(p0, p1);
  } else {
    *(uint2*)(wb + i) = *(const uint2*)((const u16*)w + i);
  }
}

// ---------------------------------------------------------------------------
// MFMA QKV projection. C[m][e] = sum_d A[m][d] * W[e][d]. (R17)
// ---------------------------------------------------------------------------
__global__ __launch_bounds__(256) void qkv_mfma_kernel(
    const void* __restrict__ x, const void* __restrict__ wqkv,
    u16* __restrict__ q, u16* __restrict__ k, u16* __restrict__ v,
    const int* __restrict__ flag)
{
  __shared__ __align__(16) u16 Ws[192 * 80];   // 30720 B
  const int tid = threadIdx.x;
  const int isf32 = *flag;
  for (int idx = tid; idx < 192 * 4; idx += 256) {
    const int row = idx >> 2, c0 = (idx & 3) * 16;
    u16 t16[16];
    if (isf32) {
      const float4* gp = (const float4*)((const float*)wqkv + row * 64 + c0);
      float4 f0 = gp[0], f1 = gp[1], f2 = gp[2], f3 = gp[3];
      t16[0]=f2bf(f0.x); t16[1]=f2bf(f0.y); t16[2]=f2bf(f0.z); t16[3]=f2bf(f0.w);
      t16[4]=f2bf(f1.x); t16[5]=f2bf(f1.y); t16[6]=f2bf(f1.z); t16[7]=f2bf(f1.w);
      t16[8]=f2bf(f2.x); t16[9]=f2bf(f2.y); t16[10]=f2bf(f2.z); t16[11]=f2bf(f2.w);
      t16[12]=f2bf(f3.x); t16[13]=f2bf(f3.y); t16[14]=f2bf(f3.z); t16[15]=f2bf(f3.w);
    } else {
      const u16* gp = (const u16*)wqkv + row * 64 + c0;
      *(uint4*)t16 = *(const uint4*)gp;
      *(uint4*)(t16 + 8) = *(const uint4*)(gp + 8);
    }
    *(uint4*)(Ws + row * 80 + c0) = *(uint4*)t16;
    *(uint4*)(Ws + row * 80 + c0 + 8) = *(uint4*)(t16 + 8);
  }
  __syncthreads();

  const int m0 = blockIdx.x * 128;
  const int w = tid >> 6, lane = tid & 63;
  const int ar = lane & 15, quad = lane >> 4;
  const int rbase = m0 + (w & 1) * 64;     // wave rows (4 row-tiles)
  const int cbase = (w >> 1) * 96;         // wave cols (6 col-tiles)

  // A fragments direct from global: [m=ar][k=ks*32+quad*8+j]
  bf16x8 af[4][2];
#pragma unroll
  for (int rt = 0; rt < 4; ++rt) {
    const size_t row = (size_t)(rbase + rt * 16 + ar) * 64;
    if (isf32) {
      const float* gp = (const float*)x + row;
#pragma unroll
      for (int ks = 0; ks < 2; ++ks) {
        const float4* g4 = (const float4*)(gp + ks * 32 + quad * 8);
        float4 f0 = g4[0], f1 = g4[1];
        u16 t8[8];
        t8[0]=f2bf(f0.x); t8[1]=f2bf(f0.y); t8[2]=f2bf(f0.z); t8[3]=f2bf(f0.w);
        t8[4]=f2bf(f1.x); t8[5]=f2bf(f1.y); t8[6]=f2bf(f1.z); t8[7]=f2bf(f1.w);
        af[rt][ks] = *(bf16x8*)t8;
      }
    } else {
      const u16* gp = (const u16*)x + row;
#pragma unroll
      for (int ks = 0; ks < 2; ++ks)
        af[rt][ks] = *(const bf16x8*)(gp + ks * 32 + quad * 8);
    }
  }

  f32x4 acc[4][6] = {};
#pragma unroll
  for (int ks = 0; ks < 2; ++ks)
#pragma unroll
    for (int t = 0; t < 6; ++t) {
      const bf16x8 bfr = *(const bf16x8*)(Ws + (cbase + t * 16 + ar) * 80 + ks * 32 + quad * 8);
#pragma unroll
      for (int rt = 0; rt < 4; ++rt)
        acc[rt][t] = __builtin_amdgcn_mfma_f32_16x16x32_bf16(af[rt][ks], bfr, acc[rt][t], 0, 0, 0);
    }

  // epilogue: m -> (z, s, h); e -> (matrix, d)
#pragma unroll
  for (int rt = 0; rt < 4; ++rt)
#pragma unroll
    for (int r = 0; r < 4; ++r) {
      const int m = rbase + rt * 16 + quad * 4 + r;
      const int z = m >> 15, s = (m >> 4) & (S_ - 1), h = m & (H_ - 1);
      const size_t base = (((size_t)z * H_ + h) * S_ + s) * HS_;
#pragma unroll
      for (int t = 0; t < 6; ++t) {
        const int e = cbase + t * 16 + ar;
        u16* dst = (e < 64) ? q : (e < 128) ? k : v;
        dst[base + (e & 63)] = f2bf(acc[rt][t][r]);
      }
    }
}

// ---------------------------------------------------------------------------
// Fallback vector QKV (per-batch mode only; unchanged from R9).
// ---------------------------------------------------------------------------
__global__ __launch_bounds__(256) void qkv_kernel(
    const void* __restrict__ x, int b0, const void* __restrict__ w,
    u16* __restrict__ q, u16* __restrict__ k, u16* __restrict__ v,
    const int* __restrict__ flag)
{
  __shared__ __align__(16) float Ws[192 * 64];
  const int tid = threadIdx.x;
  const int isf32 = *flag;
  if (isf32) {
    for (int i = tid; i < 192 * 64; i += 256) Ws[i] = ((const float*)w)[i];
  } else {
    for (int i = tid; i < 192 * 64; i += 256) Ws[i] = bf2f(((const u16*)w)[i]);
  }
  __syncthreads();

  const int th = blockIdx.x * 256 + tid;
  const int h = th & (H_ - 1);
  const int s = th >> 4;
  const int b = b0 + blockIdx.z;
  const size_t zoff = (size_t)blockIdx.z * H_ * S_ * HS_;
  const size_t xoff = ((size_t)b * S_ + s) * V_ + h * HS_;

  float xf[64];
  if (isf32) {
    const float4* xp = (const float4*)((const float*)x + xoff);
#pragma unroll
    for (int i = 0; i < 16; ++i) {
      float4 u = xp[i];
      xf[4*i+0] = u.x; xf[4*i+1] = u.y; xf[4*i+2] = u.z; xf[4*i+3] = u.w;
    }
  } else {
    const uint4* xp = (const uint4*)((const u16*)x + xoff);
#pragma unroll
    for (int i = 0; i < 8; ++i) {
      uint4 u = xp[i];
      xf[8*i+0] = lo16(u.x); xf[8*i+1] = hi16(u.x);
      xf[8*i+2] = lo16(u.y); xf[8*i+3] = hi16(u.y);
      xf[8*i+4] = lo16(u.z); xf[8*i+5] = hi16(u.z);
      xf[8*i+6] = lo16(u.w); xf[8*i+7] = hi16(u.w);
    }
  }

  const size_t obase = zoff + ((size_t)h * S_ + s) * HS_;
#pragma unroll 1
  for (int eg = 0; eg < 12; ++eg) {
    float acc[16];
#pragma unroll
    for (int ee = 0; ee < 16; ++ee) {
      const float4* wr = (const float4*)&Ws[(eg * 16 + ee) * 64];
      float a = 0.f;
#pragma unroll
      for (int d4 = 0; d4 < 16; ++d4) {
        float4 wv = wr[d4];
        a += xf[d4*4+0]*wv.x + xf[d4*4+1]*wv.y + xf[d4*4+2]*wv.z + xf[d4*4+3]*wv.w;
      }
      acc[ee] = a;
    }
    u16* dst = (eg < 4) ? q : (eg < 8) ? k : v;
    const int d0 = (eg & 3) * 16;
    unsigned int p[8];
#pragma unroll
    for (int t = 0; t < 8; ++t)
      p[t] = (unsigned int)f2bf(acc[2*t]) | ((unsigned int)f2bf(acc[2*t+1]) << 16);
    uint4* dp = (uint4*)(dst + obase + d0);
    dp[0] = make_uint4(p[0], p[1], p[2], p[3]);
    dp[1] = make_uint4(p[4], p[5], p[6], p[7]);
  }
}

// ---------------------------------------------------------------------------
// R19 MFMA flash attention. Block = 4 waves; block i owns strips i (u0) and
// 31-i (u1) -> uniform 33 tile-units/wave (R13). K/V double-buffered: one
// barrier per iteration; loads(j+1) and writes to buf[c^1] overlap compute
// on buf[c]. Swapped QK^T D[k=quad*4+r][q=col]; fixed-reference softmax
// p=exp2(s); P via cvt_pk; l partials reduced once in epilogue.
// ---------------------------------------------------------------------------
__global__ __launch_bounds__(256, 4) void attn_mfma_kernel(
    const u16* __restrict__ q, const u16* __restrict__ k,
    const u16* __restrict__ v, u16* __restrict__ o)
{
  const int z   = blockIdx.z;
  const int h   = blockIdx.y;
  const int bi  = blockIdx.x;          // 0..15
  const int qb0 = bi * 64;             // top subtile (u=0)
  const int qb1 = (31 - bi) * 64;      // bottom subtile (u=1)
  const int tid = threadIdx.x;
  const int w = tid >> 6, lane = tid & 63;
  const int col = lane & 15, quad = lane >> 4;

  __shared__ __align__(16) u16 Ks[2][64 * 72];
  __shared__ __align__(16) u16 Vt[2][64 * 72];
  __shared__ __align__(16) u16 Ps[4][16 * 72];   // 46080 B total

  const size_t hs = ((size_t)z * H_ + h) * S_ * HS_;

  // Q fragments for the two subtiles; scale folds 1/8 and log2(e).
  const float qs = 0.125f * 1.44269504089f;
  bf16x8 qf[2][2];
#pragma unroll
  for (int u = 0; u < 2; ++u) {
    const int qb = u ? qb1 : qb0;
    const u16* qp = q + hs + (size_t)(qb + w * 16 + col) * HS_ + quad * 8;
#pragma unroll
    for (int ks = 0; ks < 2; ++ks) {
      u16 t8[8];
      *(uint4*)t8 = *(const uint4*)(qp + ks * 32);
#pragma unroll
      for (int e = 0; e < 8; ++e) t8[e] = f2bf(bf2f(t8[e]) * qs);
      qf[u][ks] = *(bf16x8*)t8;
    }
  }

  const int sr = tid >> 2, sc = (tid & 3) * 16;        // K staging: 64x64
  const int vr = (tid & 31) * 2, vc = (tid >> 5) * 8;  // V staging: 2 rows x 8 cols

  f32x4 oacc[2][4] = {};
  float l_run[2] = {0.f, 0.f};         // per-lane PARTIAL row sums

  const int jbmax = qb1;               // bottom subtile's diagonal tile

  // prologue: load tile 0, stage into buf 0, publish
  uint4 k0, k1, va, vb;
  {
    const u16* kp = k + hs + (size_t)sr * HS_ + sc;
    k0 = *(const uint4*)kp;
    k1 = *(const uint4*)(kp + 8);
    const u16* vp = v + hs + (size_t)vr * HS_ + vc;
    va = *(const uint4*)vp;
    vb = *(const uint4*)(vp + HS_);
  }
  *(uint4*)(Ks[0] + sr * 72 + sc)     = k0;
  *(uint4*)(Ks[0] + sr * 72 + sc + 8) = k1;
  {
    const u16* pa = (const u16*)&va;
    const u16* pb = (const u16*)&vb;
#pragma unroll
    for (int e = 0; e < 8; ++e)
      *(unsigned int*)(Vt[0] + (vc + e) * 72 + vr) =
          (unsigned int)pa[e] | ((unsigned int)pb[e] << 16);
  }
  __syncthreads();

  for (int jb = 0; jb <= jbmax; jb += 64) {
    const int c = (jb >> 6) & 1;
    const bool more = jb < jbmax;

    if (more) {                            // issue loads for tile j+1
      const u16* kp = k + hs + (size_t)(jb + 64 + sr) * HS_ + sc;
      k0 = *(const uint4*)kp;
      k1 = *(const uint4*)(kp + 8);
      const u16* vp = v + hs + (size_t)(jb + 64 + vr) * HS_ + vc;
      va = *(const uint4*)vp;
      vb = *(const uint4*)(vp + HS_);
    }

#pragma unroll
    for (int u = 0; u < 2; ++u) {
      const int ru = (u ? qb1 : qb0) + w * 16;
      if (jb > ru + 15) continue;          // subtile fully above diagonal

      // Swapped QK^T: D[k-row = quad*4+r][q-col = col]
      f32x4 sacc[4] = {};
      __builtin_amdgcn_s_setprio(1);
#pragma unroll
      for (int ks = 0; ks < 2; ++ks)
#pragma unroll
        for (int t = 0; t < 4; ++t) {
          const bf16x8 kf = *(const bf16x8*)(Ks[c] + (t * 16 + col) * 72 + ks * 32 + quad * 8);
          sacc[t] = __builtin_amdgcn_mfma_f32_16x16x32_bf16(kf, qf[u][ks], sacc[t], 0, 0, 0);
        }
      __builtin_amdgcn_s_setprio(0);

      if (jb + 63 > ru) {                  // diagonal tile: mask k > q
        const int q_l = ru + col;
#pragma unroll
        for (int t = 0; t < 4; ++t) {
          const int kb = jb + t * 16 + quad * 4;
#pragma unroll
          for (int r = 0; r < 4; ++r)
            if (kb + r > q_l) sacc[t][r] = -INFINITY;
        }
      }

      // Fixed-reference softmax: p = exp2(s) directly (|s| <~ 16; safe).
      float ls = 0.f;
#pragma unroll
      for (int t = 0; t < 4; ++t) {
        const float p0 = __builtin_amdgcn_exp2f(sacc[t][0]);
        const float p1 = __builtin_amdgcn_exp2f(sacc[t][1]);
        const float p2 = __builtin_amdgcn_exp2f(sacc[t][2]);
        const float p3 = __builtin_amdgcn_exp2f(sacc[t][3]);
        ls += (p0 + p1) + (p2 + p3);
        *(uint2*)(Ps[w] + col * 72 + t * 16 + quad * 4) =
            make_uint2(cvtpk(p0, p1), cvtpk(p2, p3));
      }
      l_run[u] += ls;

      __builtin_amdgcn_s_setprio(1);
#pragma unroll
      for (int ks = 0; ks < 2; ++ks) {
        const bf16x8 pf = *(const bf16x8*)(Ps[w] + col * 72 + ks * 32 + quad * 8);
#pragma unroll
        for (int nt = 0; nt < 4; ++nt) {
          const bf16x8 vf = *(const bf16x8*)(Vt[c] + (nt * 16 + col) * 72 + ks * 32 + quad * 8);
          oacc[u][nt] = __builtin_amdgcn_mfma_f32_16x16x32_bf16(pf, vf, oacc[u][nt], 0, 0, 0);
        }
      }
      __builtin_amdgcn_s_setprio(0);
    }

    if (more) {                            // stage tile j+1 into other buffer
      u16* kd = Ks[c ^ 1];
      u16* vd = Vt[c ^ 1];
      *(uint4*)(kd + sr * 72 + sc)     = k0;
      *(uint4*)(kd + sr * 72 + sc + 8) = k1;
      const u16* pa = (const u16*)&va;
      const u16* pb = (const u16*)&vb;
#pragma unroll
      for (int e = 0; e < 8; ++e)
        *(unsigned int*)(vd + (vc + e) * 72 + vr) =
            (unsigned int)pa[e] | ((unsigned int)pb[e] << 16);
    }
    __syncthreads();                       // publish writes; release reads
  }

  u16* ob = o + (size_t)z * S_ * V_ + h * HS_;
#pragma unroll
  for (int u = 0; u < 2; ++u) {
    const int ru = (u ? qb1 : qb0) + w * 16;
    float lt = l_run[u];                   // reduce partials once
    lt += __shfl_xor(lt, 16);
    lt += __shfl_xor(lt, 32);
    float inv[4];
#pragma unroll
    for (int r = 0; r < 4; ++r) inv[r] = 1.0f / __shfl(lt, quad * 4 + r);
#pragma unroll
    for (int nt = 0; nt < 4; ++nt)
#pragma unroll
      for (int r = 0; r < 4; ++r)
        ob[(size_t)(ru + quad * 4 + r) * V_ + nt * 16 + col] = f2bf(oacc[u][nt][r] * inv[r]);
  }
}

// ---------------------------------------------------------------------------
// Output projection, MFMA NT-GEMM (R16 reg-prefetch). 128x128 tile, BK=32.
// ---------------------------------------------------------------------------
__global__ __launch_bounds__(256) void oproj_mfma_kernel(
    const u16* __restrict__ a, const u16* __restrict__ bw, float* __restrict__ c)
{
  __shared__ __align__(16) u16 As[128 * 40];
  __shared__ __align__(16) u16 Bs[128 * 40];
  const int tid = threadIdx.x;
  const int m0 = blockIdx.x * 128;
  const int n0 = blockIdx.y * 128;
  const int w = tid >> 6, lane = tid & 63;
  const int col = lane & 15, quad = lane >> 4;
  const int qr = (w & 1) * 64;
  const int qc = (w >> 1) * 64;

  f32x4 acc[4][4] = {};

  const int sr = tid >> 2;
  const int sk = (tid & 3) * 8;
  const u16* ga = a  + (size_t)(m0 + sr) * GK_ + sk;
  const u16* gb = bw + (size_t)(n0 + sr) * GK_ + sk;

  // prologue: stage k0 = 0
  uint4 a0 = *(const uint4*)(ga);
  uint4 a1 = *(const uint4*)(ga + (size_t)64 * GK_);
  uint4 b0 = *(const uint4*)(gb);
  uint4 b1 = *(const uint4*)(gb + (size_t)64 * GK_);

  for (int k0 = 0; k0 < GK_; k0 += 32) {
    __syncthreads();                       // prev tile reads done
    *(uint4*)(As + sr * 40 + sk)        = a0;
    *(uint4*)(As + (64 + sr) * 40 + sk) = a1;
    *(uint4*)(Bs + sr * 40 + sk)        = b0;
    *(uint4*)(Bs + (64 + sr) * 40 + sk) = b1;
    __syncthreads();

    if (k0 + 32 < GK_) {                   // prefetch k+32 under compute
      a0 = *(const uint4*)(ga + k0 + 32);
      a1 = *(const uint4*)(ga + (size_t)64 * GK_ + k0 + 32);
      b0 = *(const uint4*)(gb + k0 + 32);
      b1 = *(const uint4*)(gb + (size_t)64 * GK_ + k0 + 32);
    }

    bf16x8 af[4], bfr[4];
#pragma unroll
    for (int i = 0; i < 4; ++i) {
      af[i]  = *(const bf16x8*)(As + (qr + i * 16 + col) * 40 + quad * 8);
      bfr[i] = *(const bf16x8*)(Bs + (qc + i * 16 + col) * 40 + quad * 8);
    }
    __builtin_amdgcn_s_setprio(1);
#pragma unroll
    for (int i = 0; i < 4; ++i)
#pragma unroll
      for (int j = 0; j < 4; ++j)
        acc[i][j] = __builtin_amdgcn_mfma_f32_16x16x32_bf16(af[i], bfr[j], acc[i][j], 0, 0, 0);
    __builtin_amdgcn_s_setprio(0);
  }

#pragma unroll
  for (int i = 0; i < 4; ++i)
#pragma unroll
    for (int j = 0; j < 4; ++j)
#pragma unroll
      for (int r = 0; r < 4; ++r)
        c[(size_t)(m0 + qr + i * 16 + quad * 4 + r) * GN_ + n0 + qc + j * 16 + col]
            = acc[i][j][r];
}

// ---------------------------------------------------------------------------
// Fallback vector oproj (per-batch mode only; unchanged).
// ---------------------------------------------------------------------------
__global__ __launch_bounds__(256) void oproj_vec_kernel(
    const u16* __restrict__ o, const void* __restrict__ w,
    float* __restrict__ out, const int* __restrict__ flag)
{
  __shared__ __align__(16) float At[64 * 68];
  __shared__ __align__(16) float Wt[64 * 68];
  const int tid = threadIdx.x;
  const size_t zo = (size_t)blockIdx.z * S_ * V_;
  const int m0 = blockIdx.x * 64;
  const int n0 = blockIdx.y * 64;
  const int tr = tid >> 4, tc = tid & 15;
  const int isf32 = *flag;
  const int srow = tid >> 2, sc = (tid & 3) * 16;

  float acc[4][4] = {};

  for (int k0 = 0; k0 < GK_; k0 += 64) {
    float av[16], wv[16];
    {
      const u16* gp = o + zo + (size_t)(m0 + srow) * GK_ + k0 + sc;
      uint4 u0 = *(const uint4*)gp;
      uint4 u1 = *(const uint4*)(gp + 8);
      av[0]=lo16(u0.x); av[1]=hi16(u0.x); av[2]=lo16(u0.y); av[3]=hi16(u0.y);
      av[4]=lo16(u0.z); av[5]=hi16(u0.z); av[6]=lo16(u0.w); av[7]=hi16(u0.w);
      av[8]=lo16(u1.x); av[9]=hi16(u1.x); av[10]=lo16(u1.y); av[11]=hi16(u1.y);
      av[12]=lo16(u1.z); av[13]=hi16(u1.z); av[14]=lo16(u1.w); av[15]=hi16(u1.w);
    }
    if (isf32) {
      const float4* gp = (const float4*)((const float*)w + (size_t)(n0 + srow) * GK_ + k0 + sc);
#pragma unroll
      for (int i = 0; i < 4; ++i) {
        float4 f = gp[i];
        wv[4*i+0]=f.x; wv[4*i+1]=f.y; wv[4*i+2]=f.z; wv[4*i+3]=f.w;
      }
    } else {
      const u16* gp = (const u16*)w + (size_t)(n0 + srow) * GK_ + k0 + sc;
      uint4 u0 = *(const uint4*)gp;
      uint4 u1 = *(const uint4*)(gp + 8);
      wv[0]=lo16(u0.x); wv[1]=hi16(u0.x); wv[2]=lo16(u0.y); wv[3]=hi16(u0.y);
      wv[4]=lo16(u0.z); wv[5]=hi16(u0.z); wv[6]=lo16(u0.w); wv[7]=hi16(u0.w);
      wv[8]=lo16(u1.x); wv[9]=hi16(u1.x); wv[10]=lo16(u1.y); wv[11]=hi16(u1.y);
      wv[12]=lo16(u1.z); wv[13]=hi16(u1.z); wv[14]=lo16(u1.w); wv[15]=hi16(u1.w);
    }
    __syncthreads();
#pragma unroll
    for (int i = 0; i < 16; ++i) {
      At[(sc + i) * 68 + srow] = av[i];
      Wt[(sc + i) * 68 + srow] = wv[i];
    }
    __syncthreads();

#pragma unroll 4
    for (int kk = 0; kk < 64; ++kk) {
      float4 a4 = *(const float4*)&At[kk * 68 + tr * 4];
      float4 w4 = *(const float4*)&Wt[kk * 68 + tc * 4];
      acc[0][0] += a4.x*w4.x; acc[0][1] += a4.x*w4.y; acc[0][2] += a4.x*w4.z; acc[0][3] += a4.x*w4.w;
      acc[1][0] += a4.y*w4.x; acc[1][1] += a4.y*w4.y; acc[1][2] += a4.y*w4.z; acc[1][3] += a4.y*w4.w;
      acc[2][0] += a4.z*w4.x; acc[2][1] += a4.z*w4.y; acc[2][2] += a4.z*w4.z; acc[2][3] += a4.z*w4.w;
      acc[3][0] += a4.w*w4.x; acc[3][1] += a4.w*w4.y; acc[3][2] += a4.w*w4.z; acc[3][3] += a4.w*w4.w;
    }
  }

#pragma unroll
  for (int r = 0; r < 4; ++r) {
    const int row = m0 + tr * 4 + r;
    *(float4*)(out + zo + (size_t)row * GN_ + n0 + tc * 4) =
        make_float4(acc[r][0], acc[r][1], acc[r][2], acc[r][3]);
  }
}

// ---------------------------------------------------------------------------
extern "C" void kernel_launch(void* const* d_in, const int* in_sizes, int n_in,
                              void* d_out, int out_size, void* d_ws, size_t ws_size,
                              hipStream_t stream) {
  const void* x = d_in[0];
  const void* wqkv = (n_in > 1) ? d_in[1] : d_in[0];
  const void* wout = (n_in > 2) ? d_in[2] : d_in[0];
  for (int i = 0; i < n_in; ++i) {
    if      (in_sizes[i] == B_ * S_ * V_)  x    = d_in[i];
    else if (in_sizes[i] == 3 * HS_ * HS_) wqkv = d_in[i];
    else if (in_sizes[i] == V_ * V_)       wout = d_in[i];
  }
  float* out = (float*)d_out;

  const size_t per_b = (size_t)H_ * S_ * HS_;
  const size_t SV = (size_t)S_ * V_;
  int* flag = (int*)d_ws;
  const bool full = ws_size >= (16 + 16 * per_b * sizeof(u16));
  const size_t stride = full ? 4 * per_b : per_b;
  u16* q = (u16*)((char*)d_ws + 16);
  u16* k = q + stride;
  u16* v = k + stride;
  u16* o = v + stride;

  detect_kernel<<<dim3(1), dim3(256), 0, stream>>>((const unsigned int*)x, flag);
  if (full) {
    qkv_mfma_kernel<<<dim3((B_ * S_ * H_) / 128), dim3(256), 0, stream>>>(
        x, wqkv, q, k, v, flag);
    attn_mfma_kernel<<<dim3(16, 16, B_), dim3(256), 0, stream>>>(q, k, v, o);
    u16* wb = q;   // q dead after attn
    wcvt_kernel<<<dim3((V_ * V_) / 1024), dim3(256), 0, stream>>>(wout, wb, flag);
    oproj_mfma_kernel<<<dim3((B_ * S_) / 128, GN_ / 128), dim3(256), 0, stream>>>(o, wb, out);
  } else {
    for (int b = 0; b < B_; ++b) {
      qkv_kernel<<<dim3(128, 1, 1), dim3(256), 0, stream>>>(x, b, wqkv, q, k, v, flag);
      attn_mfma_kernel<<<dim3(16, 16, 1), dim3(256), 0, stream>>>(q, k, v, o);
      oproj_vec_kernel<<<dim3(32, 16, 1), dim3(256), 0, stream>>>(
          o, wout, out + (size_t)b * SV, flag);
    }
  }
}

// Round 12
// 211.536 us; speedup vs baseline: 1.2627x; 1.1617x over previous
//
#include <hip/hip_runtime.h>

// Causal MHA. B=4, S=2048, V=1024, H=16, hs=64. Output fp32.
// R20: attn REVERTED to R17 exactly (75.6us proven; R18 more-blocks and
// R19 fewer-barriers both regressed -> R17 is a local optimum). oproj
// upgraded BK=32 -> 64: 16 iterations (was 32), 32 MFMA/stage, LDS 36.9KB
// (grid gives 2 blocks/CU so no occupancy loss), reg-prefetch kept.
// Fixed-ref softmax + paired strips + cvt_pk in attn (R13/R15/R17).
#define B_  4
#define S_  2048
#define V_  1024
#define H_  16
#define HS_ 64
#define GK_ 1024
#define GN_ 1024

typedef unsigned short u16;
typedef __bf16 bf16x8 __attribute__((ext_vector_type(8)));
typedef float  f32x4  __attribute__((ext_vector_type(4)));

__device__ __forceinline__ float bf2f(u16 u) {
  return __uint_as_float(((unsigned int)u) << 16);
}
__device__ __forceinline__ float lo16(unsigned int w) { return __uint_as_float(w << 16); }
__device__ __forceinline__ float hi16(unsigned int w) { return __uint_as_float(w & 0xffff0000u); }
__device__ __forceinline__ u16 f2bf(float f) {
  unsigned int u = __float_as_uint(f);
  unsigned int r = u + 0x7fffu + ((u >> 16) & 1u);  // RNE
  return (u16)(r >> 16);
}
__device__ __forceinline__ unsigned int cvtpk(float lo, float hi) {
  unsigned int r;
  asm("v_cvt_pk_bf16_f32 %0, %1, %2" : "=v"(r) : "v"(lo), "v"(hi));
  return r;
}

// ---------------------------------------------------------------------------
// Input-storage detector (fp32 vs bf16; see R5/R7 notes).
// ---------------------------------------------------------------------------
__global__ __launch_bounds__(256) void detect_kernel(
    const unsigned int* __restrict__ x32, int* __restrict__ flag)
{
  __shared__ int zred[256];
  __shared__ int nred[256];
  const int tid = threadIdx.x;
  int nz = 0, nn = 0;
  for (int i = tid; i < 16384; i += 256) {
    unsigned int lo = x32[i] & 0xffffu;
    if (lo == 0u) nz++;
    if ((lo & 0x7f80u) == 0x7f80u && (lo & 0x7fu) != 0u) nn++;
  }
  zred[tid] = nz; nred[tid] = nn;
  __syncthreads();
  for (int s = 128; s > 0; s >>= 1) {
    if (tid < s) { zred[tid] += zred[tid + s]; nred[tid] += nred[tid + s]; }
    __syncthreads();
  }
  if (tid == 0) *flag = (zred[0] > 8192 || nred[0] > 0) ? 1 : 0;
}

// ---------------------------------------------------------------------------
// W_out -> bf16 (into q's dead workspace region, full mode only).
// ---------------------------------------------------------------------------
__global__ __launch_bounds__(256) void wcvt_kernel(
    const void* __restrict__ w, u16* __restrict__ wb, const int* __restrict__ flag)
{
  const int i = (blockIdx.x * 256 + threadIdx.x) * 4;
  if (*flag) {
    float4 f = *(const float4*)((const float*)w + i);
    unsigned int p0 = (unsigned int)f2bf(f.x) | ((unsigned int)f2bf(f.y) << 16);
    unsigned int p1 = (unsigned int)f2bf(f.z) | ((unsigned int)f2bf(f.w) << 16);
    *(uint2*)(wb + i) = make_uint2(p0, p1);
  } else {
    *(uint2*)(wb + i) = *(const uint2*)((const u16*)w + i);
  }
}

// ---------------------------------------------------------------------------
// MFMA QKV projection. C[m][e] = sum_d A[m][d] * W[e][d]. (R17)
// ---------------------------------------------------------------------------
__global__ __launch_bounds__(256) void qkv_mfma_kernel(
    const void* __restrict__ x, const void* __restrict__ wqkv,
    u16* __restrict__ q, u16* __restrict__ k, u16* __restrict__ v,
    const int* __restrict__ flag)
{
  __shared__ __align__(16) u16 Ws[192 * 80];   // 30720 B
  const int tid = threadIdx.x;
  const int isf32 = *flag;
  for (int idx = tid; idx < 192 * 4; idx += 256) {
    const int row = idx >> 2, c0 = (idx & 3) * 16;
    u16 t16[16];
    if (isf32) {
      const float4* gp = (const float4*)((const float*)wqkv + row * 64 + c0);
      float4 f0 = gp[0], f1 = gp[1], f2 = gp[2], f3 = gp[3];
      t16[0]=f2bf(f0.x); t16[1]=f2bf(f0.y); t16[2]=f2bf(f0.z); t16[3]=f2bf(f0.w);
      t16[4]=f2bf(f1.x); t16[5]=f2bf(f1.y); t16[6]=f2bf(f1.z); t16[7]=f2bf(f1.w);
      t16[8]=f2bf(f2.x); t16[9]=f2bf(f2.y); t16[10]=f2bf(f2.z); t16[11]=f2bf(f2.w);
      t16[12]=f2bf(f3.x); t16[13]=f2bf(f3.y); t16[14]=f2bf(f3.z); t16[15]=f2bf(f3.w);
    } else {
      const u16* gp = (const u16*)wqkv + row * 64 + c0;
      *(uint4*)t16 = *(const uint4*)gp;
      *(uint4*)(t16 + 8) = *(const uint4*)(gp + 8);
    }
    *(uint4*)(Ws + row * 80 + c0) = *(uint4*)t16;
    *(uint4*)(Ws + row * 80 + c0 + 8) = *(uint4*)(t16 + 8);
  }
  __syncthreads();

  const int m0 = blockIdx.x * 128;
  const int w = tid >> 6, lane = tid & 63;
  const int ar = lane & 15, quad = lane >> 4;
  const int rbase = m0 + (w & 1) * 64;     // wave rows (4 row-tiles)
  const int cbase = (w >> 1) * 96;         // wave cols (6 col-tiles)

  // A fragments direct from global: [m=ar][k=ks*32+quad*8+j]
  bf16x8 af[4][2];
#pragma unroll
  for (int rt = 0; rt < 4; ++rt) {
    const size_t row = (size_t)(rbase + rt * 16 + ar) * 64;
    if (isf32) {
      const float* gp = (const float*)x + row;
#pragma unroll
      for (int ks = 0; ks < 2; ++ks) {
        const float4* g4 = (const float4*)(gp + ks * 32 + quad * 8);
        float4 f0 = g4[0], f1 = g4[1];
        u16 t8[8];
        t8[0]=f2bf(f0.x); t8[1]=f2bf(f0.y); t8[2]=f2bf(f0.z); t8[3]=f2bf(f0.w);
        t8[4]=f2bf(f1.x); t8[5]=f2bf(f1.y); t8[6]=f2bf(f1.z); t8[7]=f2bf(f1.w);
        af[rt][ks] = *(bf16x8*)t8;
      }
    } else {
      const u16* gp = (const u16*)x + row;
#pragma unroll
      for (int ks = 0; ks < 2; ++ks)
        af[rt][ks] = *(const bf16x8*)(gp + ks * 32 + quad * 8);
    }
  }

  f32x4 acc[4][6] = {};
#pragma unroll
  for (int ks = 0; ks < 2; ++ks)
#pragma unroll
    for (int t = 0; t < 6; ++t) {
      const bf16x8 bfr = *(const bf16x8*)(Ws + (cbase + t * 16 + ar) * 80 + ks * 32 + quad * 8);
#pragma unroll
      for (int rt = 0; rt < 4; ++rt)
        acc[rt][t] = __builtin_amdgcn_mfma_f32_16x16x32_bf16(af[rt][ks], bfr, acc[rt][t], 0, 0, 0);
    }

  // epilogue: m -> (z, s, h); e -> (matrix, d)
#pragma unroll
  for (int rt = 0; rt < 4; ++rt)
#pragma unroll
    for (int r = 0; r < 4; ++r) {
      const int m = rbase + rt * 16 + quad * 4 + r;
      const int z = m >> 15, s = (m >> 4) & (S_ - 1), h = m & (H_ - 1);
      const size_t base = (((size_t)z * H_ + h) * S_ + s) * HS_;
#pragma unroll
      for (int t = 0; t < 6; ++t) {
        const int e = cbase + t * 16 + ar;
        u16* dst = (e < 64) ? q : (e < 128) ? k : v;
        dst[base + (e & 63)] = f2bf(acc[rt][t][r]);
      }
    }
}

// ---------------------------------------------------------------------------
// Fallback vector QKV (per-batch mode only; unchanged from R9).
// ---------------------------------------------------------------------------
__global__ __launch_bounds__(256) void qkv_kernel(
    const void* __restrict__ x, int b0, const void* __restrict__ w,
    u16* __restrict__ q, u16* __restrict__ k, u16* __restrict__ v,
    const int* __restrict__ flag)
{
  __shared__ __align__(16) float Ws[192 * 64];
  const int tid = threadIdx.x;
  const int isf32 = *flag;
  if (isf32) {
    for (int i = tid; i < 192 * 64; i += 256) Ws[i] = ((const float*)w)[i];
  } else {
    for (int i = tid; i < 192 * 64; i += 256) Ws[i] = bf2f(((const u16*)w)[i]);
  }
  __syncthreads();

  const int th = blockIdx.x * 256 + tid;
  const int h = th & (H_ - 1);
  const int s = th >> 4;
  const int b = b0 + blockIdx.z;
  const size_t zoff = (size_t)blockIdx.z * H_ * S_ * HS_;
  const size_t xoff = ((size_t)b * S_ + s) * V_ + h * HS_;

  float xf[64];
  if (isf32) {
    const float4* xp = (const float4*)((const float*)x + xoff);
#pragma unroll
    for (int i = 0; i < 16; ++i) {
      float4 u = xp[i];
      xf[4*i+0] = u.x; xf[4*i+1] = u.y; xf[4*i+2] = u.z; xf[4*i+3] = u.w;
    }
  } else {
    const uint4* xp = (const uint4*)((const u16*)x + xoff);
#pragma unroll
    for (int i = 0; i < 8; ++i) {
      uint4 u = xp[i];
      xf[8*i+0] = lo16(u.x); xf[8*i+1] = hi16(u.x);
      xf[8*i+2] = lo16(u.y); xf[8*i+3] = hi16(u.y);
      xf[8*i+4] = lo16(u.z); xf[8*i+5] = hi16(u.z);
      xf[8*i+6] = lo16(u.w); xf[8*i+7] = hi16(u.w);
    }
  }

  const size_t obase = zoff + ((size_t)h * S_ + s) * HS_;
#pragma unroll 1
  for (int eg = 0; eg < 12; ++eg) {
    float acc[16];
#pragma unroll
    for (int ee = 0; ee < 16; ++ee) {
      const float4* wr = (const float4*)&Ws[(eg * 16 + ee) * 64];
      float a = 0.f;
#pragma unroll
      for (int d4 = 0; d4 < 16; ++d4) {
        float4 wv = wr[d4];
        a += xf[d4*4+0]*wv.x + xf[d4*4+1]*wv.y + xf[d4*4+2]*wv.z + xf[d4*4+3]*wv.w;
      }
      acc[ee] = a;
    }
    u16* dst = (eg < 4) ? q : (eg < 8) ? k : v;
    const int d0 = (eg & 3) * 16;
    unsigned int p[8];
#pragma unroll
    for (int t = 0; t < 8; ++t)
      p[t] = (unsigned int)f2bf(acc[2*t]) | ((unsigned int)f2bf(acc[2*t+1]) << 16);
    uint4* dp = (uint4*)(dst + obase + d0);
    dp[0] = make_uint4(p[0], p[1], p[2], p[3]);
    dp[1] = make_uint4(p[4], p[5], p[6], p[7]);
  }
}

// ---------------------------------------------------------------------------
// R17 MFMA flash attention (reverted; best measured 75.6us). Block = 4
// waves; block i owns strips i (u0) and 31-i (u1) -> uniform 33 tile-units/
// wave. Swapped QK^T D[k=quad*4+r][q=col]. Fixed-reference softmax:
// p = exp2(s) directly. P packed via cvt_pk; l partials reduced in epilogue.
// ---------------------------------------------------------------------------
__global__ __launch_bounds__(256, 4) void attn_mfma_kernel(
    const u16* __restrict__ q, const u16* __restrict__ k,
    const u16* __restrict__ v, u16* __restrict__ o)
{
  const int z   = blockIdx.z;
  const int h   = blockIdx.y;
  const int bi  = blockIdx.x;          // 0..15
  const int qb0 = bi * 64;             // top subtile (u=0)
  const int qb1 = (31 - bi) * 64;      // bottom subtile (u=1)
  const int tid = threadIdx.x;
  const int w = tid >> 6, lane = tid & 63;
  const int col = lane & 15, quad = lane >> 4;

  __shared__ __align__(16) u16 Ks[64 * 72];
  __shared__ __align__(16) u16 Vt[64 * 72];
  __shared__ __align__(16) u16 Ps[4][16 * 72];

  const size_t hs = ((size_t)z * H_ + h) * S_ * HS_;

  // Q fragments for the two subtiles; scale folds 1/8 and log2(e).
  const float qs = 0.125f * 1.44269504089f;
  bf16x8 qf[2][2];
#pragma unroll
  for (int u = 0; u < 2; ++u) {
    const int qb = u ? qb1 : qb0;
    const u16* qp = q + hs + (size_t)(qb + w * 16 + col) * HS_ + quad * 8;
#pragma unroll
    for (int ks = 0; ks < 2; ++ks) {
      u16 t8[8];
      *(uint4*)t8 = *(const uint4*)(qp + ks * 32);
#pragma unroll
      for (int e = 0; e < 8; ++e) t8[e] = f2bf(bf2f(t8[e]) * qs);
      qf[u][ks] = *(bf16x8*)t8;
    }
  }

  const int sr = tid >> 2, sc = (tid & 3) * 16;        // K staging: 64x64
  const int vr = (tid & 31) * 2, vc = (tid >> 5) * 8;  // V staging: 2 rows x 8 cols

  f32x4 oacc[2][4] = {};
  float l_run[2] = {0.f, 0.f};         // per-lane PARTIAL row sums

  const int jbmax = qb1;               // bottom subtile's diagonal tile

  // prologue: load tile 0
  uint4 k0, k1, va, vb;
  {
    const u16* kp = k + hs + (size_t)sr * HS_ + sc;
    k0 = *(const uint4*)kp;
    k1 = *(const uint4*)(kp + 8);
    const u16* vp = v + hs + (size_t)vr * HS_ + vc;
    va = *(const uint4*)vp;
    vb = *(const uint4*)(vp + HS_);
  }

  for (int jb = 0; jb <= jbmax; jb += 64) {
    __syncthreads();                       // all waves done reading prev tile
    *(uint4*)(Ks + sr * 72 + sc)     = k0;
    *(uint4*)(Ks + sr * 72 + sc + 8) = k1;
    {
      const u16* pa = (const u16*)&va;
      const u16* pb = (const u16*)&vb;
#pragma unroll
      for (int e = 0; e < 8; ++e)
        *(unsigned int*)(Vt + (vc + e) * 72 + vr) =
            (unsigned int)pa[e] | ((unsigned int)pb[e] << 16);
    }
    __syncthreads();

    if (jb < jbmax) {                      // prefetch next tile under compute
      const u16* kp = k + hs + (size_t)(jb + 64 + sr) * HS_ + sc;
      k0 = *(const uint4*)kp;
      k1 = *(const uint4*)(kp + 8);
      const u16* vp = v + hs + (size_t)(jb + 64 + vr) * HS_ + vc;
      va = *(const uint4*)vp;
      vb = *(const uint4*)(vp + HS_);
    }

#pragma unroll
    for (int u = 0; u < 2; ++u) {
      const int ru = (u ? qb1 : qb0) + w * 16;
      if (jb > ru + 15) continue;          // subtile fully above diagonal

      // Swapped QK^T: D[k-row = quad*4+r][q-col = col]
      f32x4 sacc[4] = {};
      __builtin_amdgcn_s_setprio(1);
#pragma unroll
      for (int ks = 0; ks < 2; ++ks)
#pragma unroll
        for (int t = 0; t < 4; ++t) {
          const bf16x8 kf = *(const bf16x8*)(Ks + (t * 16 + col) * 72 + ks * 32 + quad * 8);
          sacc[t] = __builtin_amdgcn_mfma_f32_16x16x32_bf16(kf, qf[u][ks], sacc[t], 0, 0, 0);
        }
      __builtin_amdgcn_s_setprio(0);

      if (jb + 63 > ru) {                  // diagonal tile: mask k > q
        const int q_l = ru + col;
#pragma unroll
        for (int t = 0; t < 4; ++t) {
          const int kb = jb + t * 16 + quad * 4;
#pragma unroll
          for (int r = 0; r < 4; ++r)
            if (kb + r > q_l) sacc[t][r] = -INFINITY;
        }
      }

      // Fixed-reference softmax: p = exp2(s) directly (|s| <~ 16; safe).
      float ls = 0.f;
#pragma unroll
      for (int t = 0; t < 4; ++t) {
        const float p0 = __builtin_amdgcn_exp2f(sacc[t][0]);
        const float p1 = __builtin_amdgcn_exp2f(sacc[t][1]);
        const float p2 = __builtin_amdgcn_exp2f(sacc[t][2]);
        const float p3 = __builtin_amdgcn_exp2f(sacc[t][3]);
        ls += (p0 + p1) + (p2 + p3);
        *(uint2*)(Ps[w] + col * 72 + t * 16 + quad * 4) =
            make_uint2(cvtpk(p0, p1), cvtpk(p2, p3));
      }
      l_run[u] += ls;

      __builtin_amdgcn_s_setprio(1);
#pragma unroll
      for (int ks = 0; ks < 2; ++ks) {
        const bf16x8 pf = *(const bf16x8*)(Ps[w] + col * 72 + ks * 32 + quad * 8);
#pragma unroll
        for (int nt = 0; nt < 4; ++nt) {
          const bf16x8 vf = *(const bf16x8*)(Vt + (nt * 16 + col) * 72 + ks * 32 + quad * 8);
          oacc[u][nt] = __builtin_amdgcn_mfma_f32_16x16x32_bf16(pf, vf, oacc[u][nt], 0, 0, 0);
        }
      }
      __builtin_amdgcn_s_setprio(0);
    }
  }

  u16* ob = o + (size_t)z * S_ * V_ + h * HS_;
#pragma unroll
  for (int u = 0; u < 2; ++u) {
    const int ru = (u ? qb1 : qb0) + w * 16;
    float lt = l_run[u];                   // reduce partials once
    lt += __shfl_xor(lt, 16);
    lt += __shfl_xor(lt, 32);
    float inv[4];
#pragma unroll
    for (int r = 0; r < 4; ++r) inv[r] = 1.0f / __shfl(lt, quad * 4 + r);
#pragma unroll
    for (int nt = 0; nt < 4; ++nt)
#pragma unroll
      for (int r = 0; r < 4; ++r)
        ob[(size_t)(ru + quad * 4 + r) * V_ + nt * 16 + col] = f2bf(oacc[u][nt][r] * inv[r]);
  }
}

// ---------------------------------------------------------------------------
// Output projection, MFMA NT-GEMM. R20: BK=64 (16 iterations, 32 MFMA/stage,
// half the barriers), reg-prefetch kept. LDS 2x128x72 u16 = 36.9KB.
// ---------------------------------------------------------------------------
__global__ __launch_bounds__(256) void oproj_mfma_kernel(
    const u16* __restrict__ a, const u16* __restrict__ bw, float* __restrict__ c)
{
  __shared__ __align__(16) u16 As[128 * 72];
  __shared__ __align__(16) u16 Bs[128 * 72];
  const int tid = threadIdx.x;
  const int m0 = blockIdx.x * 128;
  const int n0 = blockIdx.y * 128;
  const int w = tid >> 6, lane = tid & 63;
  const int col = lane & 15, quad = lane >> 4;
  const int qr = (w & 1) * 64;
  const int qc = (w >> 1) * 64;

  f32x4 acc[4][4] = {};

  const int sr = tid >> 2;            // 0..63
  const int sk = (tid & 3) * 16;      // 0,16,32,48 (u16 units)
  const u16* ga = a  + (size_t)(m0 + sr) * GK_ + sk;
  const u16* gb = bw + (size_t)(n0 + sr) * GK_ + sk;

  // prologue: stage k0 = 0 (rows sr and sr+64, 2 uint4 each per matrix)
  uint4 a0 = *(const uint4*)(ga);
  uint4 a1 = *(const uint4*)(ga + 8);
  uint4 a2 = *(const uint4*)(ga + (size_t)64 * GK_);
  uint4 a3 = *(const uint4*)(ga + (size_t)64 * GK_ + 8);
  uint4 b0 = *(const uint4*)(gb);
  uint4 b1 = *(const uint4*)(gb + 8);
  uint4 b2 = *(const uint4*)(gb + (size_t)64 * GK_);
  uint4 b3 = *(const uint4*)(gb + (size_t)64 * GK_ + 8);

  for (int k0 = 0; k0 < GK_; k0 += 64) {
    __syncthreads();                       // prev tile reads done
    *(uint4*)(As + sr * 72 + sk)            = a0;
    *(uint4*)(As + sr * 72 + sk + 8)        = a1;
    *(uint4*)(As + (64 + sr) * 72 + sk)     = a2;
    *(uint4*)(As + (64 + sr) * 72 + sk + 8) = a3;
    *(uint4*)(Bs + sr * 72 + sk)            = b0;
    *(uint4*)(Bs + sr * 72 + sk + 8)        = b1;
    *(uint4*)(Bs + (64 + sr) * 72 + sk)     = b2;
    *(uint4*)(Bs + (64 + sr) * 72 + sk + 8) = b3;
    __syncthreads();

    if (k0 + 64 < GK_) {                   // prefetch k+64 under compute
      a0 = *(const uint4*)(ga + k0 + 64);
      a1 = *(const uint4*)(ga + k0 + 64 + 8);
      a2 = *(const uint4*)(ga + (size_t)64 * GK_ + k0 + 64);
      a3 = *(const uint4*)(ga + (size_t)64 * GK_ + k0 + 64 + 8);
      b0 = *(const uint4*)(gb + k0 + 64);
      b1 = *(const uint4*)(gb + k0 + 64 + 8);
      b2 = *(const uint4*)(gb + (size_t)64 * GK_ + k0 + 64);
      b3 = *(const uint4*)(gb + (size_t)64 * GK_ + k0 + 64 + 8);
    }

#pragma unroll
    for (int ks = 0; ks < 2; ++ks) {
      bf16x8 af[4], bfr[4];
#pragma unroll
      for (int i = 0; i < 4; ++i) {
        af[i]  = *(const bf16x8*)(As + (qr + i * 16 + col) * 72 + ks * 32 + quad * 8);
        bfr[i] = *(const bf16x8*)(Bs + (qc + i * 16 + col) * 72 + ks * 32 + quad * 8);
      }
      __builtin_amdgcn_s_setprio(1);
#pragma unroll
      for (int i = 0; i < 4; ++i)
#pragma unroll
        for (int j = 0; j < 4; ++j)
          acc[i][j] = __builtin_amdgcn_mfma_f32_16x16x32_bf16(af[i], bfr[j], acc[i][j], 0, 0, 0);
      __builtin_amdgcn_s_setprio(0);
    }
  }

#pragma unroll
  for (int i = 0; i < 4; ++i)
#pragma unroll
    for (int j = 0; j < 4; ++j)
#pragma unroll
      for (int r = 0; r < 4; ++r)
        c[(size_t)(m0 + qr + i * 16 + quad * 4 + r) * GN_ + n0 + qc + j * 16 + col]
            = acc[i][j][r];
}

// ---------------------------------------------------------------------------
// Fallback vector oproj (per-batch mode only; unchanged).
// ---------------------------------------------------------------------------
__global__ __launch_bounds__(256) void oproj_vec_kernel(
    const u16* __restrict__ o, const void* __restrict__ w,
    float* __restrict__ out, const int* __restrict__ flag)
{
  __shared__ __align__(16) float At[64 * 68];
  __shared__ __align__(16) float Wt[64 * 68];
  const int tid = threadIdx.x;
  const size_t zo = (size_t)blockIdx.z * S_ * V_;
  const int m0 = blockIdx.x * 64;
  const int n0 = blockIdx.y * 64;
  const int tr = tid >> 4, tc = tid & 15;
  const int isf32 = *flag;
  const int srow = tid >> 2, sc = (tid & 3) * 16;

  float acc[4][4] = {};

  for (int k0 = 0; k0 < GK_; k0 += 64) {
    float av[16], wv[16];
    {
      const u16* gp = o + zo + (size_t)(m0 + srow) * GK_ + k0 + sc;
      uint4 u0 = *(const uint4*)gp;
      uint4 u1 = *(const uint4*)(gp + 8);
      av[0]=lo16(u0.x); av[1]=hi16(u0.x); av[2]=lo16(u0.y); av[3]=hi16(u0.y);
      av[4]=lo16(u0.z); av[5]=hi16(u0.z); av[6]=lo16(u0.w); av[7]=hi16(u0.w);
      av[8]=lo16(u1.x); av[9]=hi16(u1.x); av[10]=lo16(u1.y); av[11]=hi16(u1.y);
      av[12]=lo16(u1.z); av[13]=hi16(u1.z); av[14]=lo16(u1.w); av[15]=hi16(u1.w);
    }
    if (isf32) {
      const float4* gp = (const float4*)((const float*)w + (size_t)(n0 + srow) * GK_ + k0 + sc);
#pragma unroll
      for (int i = 0; i < 4; ++i) {
        float4 f = gp[i];
        wv[4*i+0]=f.x; wv[4*i+1]=f.y; wv[4*i+2]=f.z; wv[4*i+3]=f.w;
      }
    } else {
      const u16* gp = (const u16*)w + (size_t)(n0 + srow) * GK_ + k0 + sc;
      uint4 u0 = *(const uint4*)gp;
      uint4 u1 = *(const uint4*)(gp + 8);
      wv[0]=lo16(u0.x); wv[1]=hi16(u0.x); wv[2]=lo16(u0.y); wv[3]=hi16(u0.y);
      wv[4]=lo16(u0.z); wv[5]=hi16(u0.z); wv[6]=lo16(u0.w); wv[7]=hi16(u0.w);
      wv[8]=lo16(u1.x); wv[9]=hi16(u1.x); wv[10]=lo16(u1.y); wv[11]=hi16(u1.y);
      wv[12]=lo16(u1.z); wv[13]=hi16(u1.z); wv[14]=lo16(u1.w); wv[15]=hi16(u1.w);
    }
    __syncthreads();
#pragma unroll
    for (int i = 0; i < 16; ++i) {
      At[(sc + i) * 68 + srow] = av[i];
      Wt[(sc + i) * 68 + srow] = wv[i];
    }
    __syncthreads();

#pragma unroll 4
    for (int kk = 0; kk < 64; ++kk) {
      float4 a4 = *(const float4*)&At[kk * 68 + tr * 4];
      float4 w4 = *(const float4*)&Wt[kk * 68 + tc * 4];
      acc[0][0] += a4.x*w4.x; acc[0][1] += a4.x*w4.y; acc[0][2] += a4.x*w4.z; acc[0][3] += a4.x*w4.w;
      acc[1][0] += a4.y*w4.x; acc[1][1] += a4.y*w4.y; acc[1][2] += a4.y*w4.z; acc[1][3] += a4.y*w4.w;
      acc[2][0] += a4.z*w4.x; acc[2][1] += a4.z*w4.y; acc[2][2] += a4.z*w4.z; acc[2][3] += a4.z*w4.w;
      acc[3][0] += a4.w*w4.x; acc[3][1] += a4.w*w4.y; acc[3][2] += a4.w*w4.z; acc[3][3] += a4.w*w4.w;
    }
  }

#pragma unroll
  for (int r = 0; r < 4; ++r) {
    const int row = m0 + tr * 4 + r;
    *(float4*)(out + zo + (size_t)row * GN_ + n0 + tc * 4) =
        make_float4(acc[r][0], acc[r][1], acc[r][2], acc[r][3]);
  }
}

// ---------------------------------------------------------------------------
extern "C" void kernel_launch(void* const* d_in, const int* in_sizes, int n_in,
                              void* d_out, int out_size, void* d_ws, size_t ws_size,
                              hipStream_t stream) {
  const void* x = d_in[0];
  const void* wqkv = (n_in > 1) ? d_in[1] : d_in[0];
  const void* wout = (n_in > 2) ? d_in[2] : d_in[0];
  for (int i = 0; i < n_in; ++i) {
    if      (in_sizes[i] == B_ * S_ * V_)  x    = d_in[i];
    else if (in_sizes[i] == 3 * HS_ * HS_) wqkv = d_in[i];
    else if (in_sizes[i] == V_ * V_)       wout = d_in[i];
  }
  float* out = (float*)d_out;

  const size_t per_b = (size_t)H_ * S_ * HS_;
  const size_t SV = (size_t)S_ * V_;
  int* flag = (int*)d_ws;
  const bool full = ws_size >= (16 + 16 * per_b * sizeof(u16));
  const size_t stride = full ? 4 * per_b : per_b;
  u16* q = (u16*)((char*)d_ws + 16);
  u16* k = q + stride;
  u16* v = k + stride;
  u16* o = v + stride;

  detect_kernel<<<dim3(1), dim3(256), 0, stream>>>((const unsigned int*)x, flag);
  if (full) {
    qkv_mfma_kernel<<<dim3((B_ * S_ * H_) / 128), dim3(256), 0, stream>>>(
        x, wqkv, q, k, v, flag);
    attn_mfma_kernel<<<dim3(16, 16, B_), dim3(256), 0, stream>>>(q, k, v, o);
    u16* wb = q;   // q dead after attn
    wcvt_kernel<<<dim3((V_ * V_) / 1024), dim3(256), 0, stream>>>(wout, wb, flag);
    oproj_mfma_kernel<<<dim3((B_ * S_) / 128, GN_ / 128), dim3(256), 0, stream>>>(o, wb, out);
  } else {
    for (int b = 0; b < B_; ++b) {
      qkv_kernel<<<dim3(128, 1, 1), dim3(256), 0, stream>>>(x, b, wqkv, q, k, v, flag);
      attn_mfma_kernel<<<dim3(16, 16, 1), dim3(256), 0, stream>>>(q, k, v, o);
      oproj_vec_kernel<<<dim3(32, 16, 1), dim3(256), 0, stream>>>(
          o, wout, out + (size_t)b * SV, flag);
    }
  }
}

// Round 13
// 211.347 us; speedup vs baseline: 1.2638x; 1.0009x over previous
//
#include <hip/hip_runtime.h>

// Causal MHA. B=4, S=2048, V=1024, H=16, hs=64. Output fp32.
// R21: qkv epilogue rebuilt via operand swap — acc = mfma(W_frag, A_frag)
// puts e in D-rows (quad*4+r) and m in D-cols (ar): each lane holds 4
// CONSECUTIVE d-values of one output row -> 2 cvtpk + 1 uint2 store per
// (rt,t). 24x 8B stores/thread (was 96 scalar u16 stores + ~384 VALU pack).
// attn (R17, 74.5us local optimum) and oproj (R20 BK=64) unchanged.
#define B_  4
#define S_  2048
#define V_  1024
#define H_  16
#define HS_ 64
#define GK_ 1024
#define GN_ 1024

typedef unsigned short u16;
typedef __bf16 bf16x8 __attribute__((ext_vector_type(8)));
typedef float  f32x4  __attribute__((ext_vector_type(4)));

__device__ __forceinline__ float bf2f(u16 u) {
  return __uint_as_float(((unsigned int)u) << 16);
}
__device__ __forceinline__ float lo16(unsigned int w) { return __uint_as_float(w << 16); }
__device__ __forceinline__ float hi16(unsigned int w) { return __uint_as_float(w & 0xffff0000u); }
__device__ __forceinline__ u16 f2bf(float f) {
  unsigned int u = __float_as_uint(f);
  unsigned int r = u + 0x7fffu + ((u >> 16) & 1u);  // RNE
  return (u16)(r >> 16);
}
__device__ __forceinline__ unsigned int cvtpk(float lo, float hi) {
  unsigned int r;
  asm("v_cvt_pk_bf16_f32 %0, %1, %2" : "=v"(r) : "v"(lo), "v"(hi));
  return r;
}

// ---------------------------------------------------------------------------
// Input-storage detector (fp32 vs bf16; see R5/R7 notes).
// ---------------------------------------------------------------------------
__global__ __launch_bounds__(256) void detect_kernel(
    const unsigned int* __restrict__ x32, int* __restrict__ flag)
{
  __shared__ int zred[256];
  __shared__ int nred[256];
  const int tid = threadIdx.x;
  int nz = 0, nn = 0;
  for (int i = tid; i < 16384; i += 256) {
    unsigned int lo = x32[i] & 0xffffu;
    if (lo == 0u) nz++;
    if ((lo & 0x7f80u) == 0x7f80u && (lo & 0x7fu) != 0u) nn++;
  }
  zred[tid] = nz; nred[tid] = nn;
  __syncthreads();
  for (int s = 128; s > 0; s >>= 1) {
    if (tid < s) { zred[tid] += zred[tid + s]; nred[tid] += nred[tid + s]; }
    __syncthreads();
  }
  if (tid == 0) *flag = (zred[0] > 8192 || nred[0] > 0) ? 1 : 0;
}

// ---------------------------------------------------------------------------
// W_out -> bf16 (into q's dead workspace region, full mode only).
// ---------------------------------------------------------------------------
__global__ __launch_bounds__(256) void wcvt_kernel(
    const void* __restrict__ w, u16* __restrict__ wb, const int* __restrict__ flag)
{
  const int i = (blockIdx.x * 256 + threadIdx.x) * 4;
  if (*flag) {
    float4 f = *(const float4*)((const float*)w + i);
    unsigned int p0 = (unsigned int)f2bf(f.x) | ((unsigned int)f2bf(f.y) << 16);
    unsigned int p1 = (unsigned int)f2bf(f.z) | ((unsigned int)f2bf(f.w) << 16);
    *(uint2*)(wb + i) = make_uint2(p0, p1);
  } else {
    *(uint2*)(wb + i) = *(const uint2*)((const u16*)w + i);
  }
}

// ---------------------------------------------------------------------------
// MFMA QKV projection. C[m][e] = sum_d A[m][d] * W[e][d].
// R21: operand-swapped MFMA -> D[row=e(quad*4+r)][col=m(ar)]; epilogue
// packs 4 consecutive d per lane via cvtpk into uint2 stores.
// ---------------------------------------------------------------------------
__global__ __launch_bounds__(256) void qkv_mfma_kernel(
    const void* __restrict__ x, const void* __restrict__ wqkv,
    u16* __restrict__ q, u16* __restrict__ k, u16* __restrict__ v,
    const int* __restrict__ flag)
{
  __shared__ __align__(16) u16 Ws[192 * 80];   // 30720 B
  const int tid = threadIdx.x;
  const int isf32 = *flag;
  for (int idx = tid; idx < 192 * 4; idx += 256) {
    const int row = idx >> 2, c0 = (idx & 3) * 16;
    u16 t16[16];
    if (isf32) {
      const float4* gp = (const float4*)((const float*)wqkv + row * 64 + c0);
      float4 f0 = gp[0], f1 = gp[1], f2 = gp[2], f3 = gp[3];
      t16[0]=f2bf(f0.x); t16[1]=f2bf(f0.y); t16[2]=f2bf(f0.z); t16[3]=f2bf(f0.w);
      t16[4]=f2bf(f1.x); t16[5]=f2bf(f1.y); t16[6]=f2bf(f1.z); t16[7]=f2bf(f1.w);
      t16[8]=f2bf(f2.x); t16[9]=f2bf(f2.y); t16[10]=f2bf(f2.z); t16[11]=f2bf(f2.w);
      t16[12]=f2bf(f3.x); t16[13]=f2bf(f3.y); t16[14]=f2bf(f3.z); t16[15]=f2bf(f3.w);
    } else {
      const u16* gp = (const u16*)wqkv + row * 64 + c0;
      *(uint4*)t16 = *(const uint4*)gp;
      *(uint4*)(t16 + 8) = *(const uint4*)(gp + 8);
    }
    *(uint4*)(Ws + row * 80 + c0) = *(uint4*)t16;
    *(uint4*)(Ws + row * 80 + c0 + 8) = *(uint4*)(t16 + 8);
  }
  __syncthreads();

  const int m0 = blockIdx.x * 128;
  const int w = tid >> 6, lane = tid & 63;
  const int ar = lane & 15, quad = lane >> 4;
  const int rbase = m0 + (w & 1) * 64;     // wave rows (4 row-tiles)
  const int cbase = (w >> 1) * 96;         // wave cols (6 col-tiles)

  // A fragments direct from global: [m=ar][k=ks*32+quad*8+j]
  bf16x8 af[4][2];
#pragma unroll
  for (int rt = 0; rt < 4; ++rt) {
    const size_t row = (size_t)(rbase + rt * 16 + ar) * 64;
    if (isf32) {
      const float* gp = (const float*)x + row;
#pragma unroll
      for (int ks = 0; ks < 2; ++ks) {
        const float4* g4 = (const float4*)(gp + ks * 32 + quad * 8);
        float4 f0 = g4[0], f1 = g4[1];
        u16 t8[8];
        t8[0]=f2bf(f0.x); t8[1]=f2bf(f0.y); t8[2]=f2bf(f0.z); t8[3]=f2bf(f0.w);
        t8[4]=f2bf(f1.x); t8[5]=f2bf(f1.y); t8[6]=f2bf(f1.z); t8[7]=f2bf(f1.w);
        af[rt][ks] = *(bf16x8*)t8;
      }
    } else {
      const u16* gp = (const u16*)x + row;
#pragma unroll
      for (int ks = 0; ks < 2; ++ks)
        af[rt][ks] = *(const bf16x8*)(gp + ks * 32 + quad * 8);
    }
  }

  f32x4 acc[4][6] = {};
#pragma unroll
  for (int ks = 0; ks < 2; ++ks)
#pragma unroll
    for (int t = 0; t < 6; ++t) {
      const bf16x8 bfr = *(const bf16x8*)(Ws + (cbase + t * 16 + ar) * 80 + ks * 32 + quad * 8);
#pragma unroll
      for (int rt = 0; rt < 4; ++rt)
        acc[rt][t] = __builtin_amdgcn_mfma_f32_16x16x32_bf16(bfr, af[rt][ks], acc[rt][t], 0, 0, 0);
    }

  // epilogue (swapped layout): lane holds e = cbase+t*16+quad*4+r (r=0..3)
  // for row m = rbase + rt*16 + ar -> pack 4 consecutive d as uint2.
#pragma unroll
  for (int rt = 0; rt < 4; ++rt) {
    const int m = rbase + rt * 16 + ar;
    const int z = m >> 15, s = (m >> 4) & (S_ - 1), h = m & (H_ - 1);
    const size_t base = (((size_t)z * H_ + h) * S_ + s) * HS_;
#pragma unroll
    for (int t = 0; t < 6; ++t) {
      const int e0 = cbase + t * 16 + quad * 4;
      u16* dst = (e0 < 64) ? q : (e0 < 128) ? k : v;
      const unsigned int w0 = cvtpk(acc[rt][t][0], acc[rt][t][1]);
      const unsigned int w1 = cvtpk(acc[rt][t][2], acc[rt][t][3]);
      *(uint2*)(dst + base + (e0 & 63)) = make_uint2(w0, w1);
    }
  }
}

// ---------------------------------------------------------------------------
// Fallback vector QKV (per-batch mode only; unchanged from R9).
// ---------------------------------------------------------------------------
__global__ __launch_bounds__(256) void qkv_kernel(
    const void* __restrict__ x, int b0, const void* __restrict__ w,
    u16* __restrict__ q, u16* __restrict__ k, u16* __restrict__ v,
    const int* __restrict__ flag)
{
  __shared__ __align__(16) float Ws[192 * 64];
  const int tid = threadIdx.x;
  const int isf32 = *flag;
  if (isf32) {
    for (int i = tid; i < 192 * 64; i += 256) Ws[i] = ((const float*)w)[i];
  } else {
    for (int i = tid; i < 192 * 64; i += 256) Ws[i] = bf2f(((const u16*)w)[i]);
  }
  __syncthreads();

  const int th = blockIdx.x * 256 + tid;
  const int h = th & (H_ - 1);
  const int s = th >> 4;
  const int b = b0 + blockIdx.z;
  const size_t zoff = (size_t)blockIdx.z * H_ * S_ * HS_;
  const size_t xoff = ((size_t)b * S_ + s) * V_ + h * HS_;

  float xf[64];
  if (isf32) {
    const float4* xp = (const float4*)((const float*)x + xoff);
#pragma unroll
    for (int i = 0; i < 16; ++i) {
      float4 u = xp[i];
      xf[4*i+0] = u.x; xf[4*i+1] = u.y; xf[4*i+2] = u.z; xf[4*i+3] = u.w;
    }
  } else {
    const uint4* xp = (const uint4*)((const u16*)x + xoff);
#pragma unroll
    for (int i = 0; i < 8; ++i) {
      uint4 u = xp[i];
      xf[8*i+0] = lo16(u.x); xf[8*i+1] = hi16(u.x);
      xf[8*i+2] = lo16(u.y); xf[8*i+3] = hi16(u.y);
      xf[8*i+4] = lo16(u.z); xf[8*i+5] = hi16(u.z);
      xf[8*i+6] = lo16(u.w); xf[8*i+7] = hi16(u.w);
    }
  }

  const size_t obase = zoff + ((size_t)h * S_ + s) * HS_;
#pragma unroll 1
  for (int eg = 0; eg < 12; ++eg) {
    float acc[16];
#pragma unroll
    for (int ee = 0; ee < 16; ++ee) {
      const float4* wr = (const float4*)&Ws[(eg * 16 + ee) * 64];
      float a = 0.f;
#pragma unroll
      for (int d4 = 0; d4 < 16; ++d4) {
        float4 wv = wr[d4];
        a += xf[d4*4+0]*wv.x + xf[d4*4+1]*wv.y + xf[d4*4+2]*wv.z + xf[d4*4+3]*wv.w;
      }
      acc[ee] = a;
    }
    u16* dst = (eg < 4) ? q : (eg < 8) ? k : v;
    const int d0 = (eg & 3) * 16;
    unsigned int p[8];
#pragma unroll
    for (int t = 0; t < 8; ++t)
      p[t] = (unsigned int)f2bf(acc[2*t]) | ((unsigned int)f2bf(acc[2*t+1]) << 16);
    uint4* dp = (uint4*)(dst + obase + d0);
    dp[0] = make_uint4(p[0], p[1], p[2], p[3]);
    dp[1] = make_uint4(p[4], p[5], p[6], p[7]);
  }
}

// ---------------------------------------------------------------------------
// R17 MFMA flash attention (local optimum, 74.5us). Block = 4 waves; block i
// owns strips i (u0) and 31-i (u1) -> uniform 33 tile-units/wave. Swapped
// QK^T D[k=quad*4+r][q=col]. Fixed-reference softmax: p = exp2(s) directly.
// P packed via cvt_pk; l partials reduced in epilogue.
// ---------------------------------------------------------------------------
__global__ __launch_bounds__(256, 4) void attn_mfma_kernel(
    const u16* __restrict__ q, const u16* __restrict__ k,
    const u16* __restrict__ v, u16* __restrict__ o)
{
  const int z   = blockIdx.z;
  const int h   = blockIdx.y;
  const int bi  = blockIdx.x;          // 0..15
  const int qb0 = bi * 64;             // top subtile (u=0)
  const int qb1 = (31 - bi) * 64;      // bottom subtile (u=1)
  const int tid = threadIdx.x;
  const int w = tid >> 6, lane = tid & 63;
  const int col = lane & 15, quad = lane >> 4;

  __shared__ __align__(16) u16 Ks[64 * 72];
  __shared__ __align__(16) u16 Vt[64 * 72];
  __shared__ __align__(16) u16 Ps[4][16 * 72];

  const size_t hs = ((size_t)z * H_ + h) * S_ * HS_;

  // Q fragments for the two subtiles; scale folds 1/8 and log2(e).
  const float qs = 0.125f * 1.44269504089f;
  bf16x8 qf[2][2];
#pragma unroll
  for (int u = 0; u < 2; ++u) {
    const int qb = u ? qb1 : qb0;
    const u16* qp = q + hs + (size_t)(qb + w * 16 + col) * HS_ + quad * 8;
#pragma unroll
    for (int ks = 0; ks < 2; ++ks) {
      u16 t8[8];
      *(uint4*)t8 = *(const uint4*)(qp + ks * 32);
#pragma unroll
      for (int e = 0; e < 8; ++e) t8[e] = f2bf(bf2f(t8[e]) * qs);
      qf[u][ks] = *(bf16x8*)t8;
    }
  }

  const int sr = tid >> 2, sc = (tid & 3) * 16;        // K staging: 64x64
  const int vr = (tid & 31) * 2, vc = (tid >> 5) * 8;  // V staging: 2 rows x 8 cols

  f32x4 oacc[2][4] = {};
  float l_run[2] = {0.f, 0.f};         // per-lane PARTIAL row sums

  const int jbmax = qb1;               // bottom subtile's diagonal tile

  // prologue: load tile 0
  uint4 k0, k1, va, vb;
  {
    const u16* kp = k + hs + (size_t)sr * HS_ + sc;
    k0 = *(const uint4*)kp;
    k1 = *(const uint4*)(kp + 8);
    const u16* vp = v + hs + (size_t)vr * HS_ + vc;
    va = *(const uint4*)vp;
    vb = *(const uint4*)(vp + HS_);
  }

  for (int jb = 0; jb <= jbmax; jb += 64) {
    __syncthreads();                       // all waves done reading prev tile
    *(uint4*)(Ks + sr * 72 + sc)     = k0;
    *(uint4*)(Ks + sr * 72 + sc + 8) = k1;
    {
      const u16* pa = (const u16*)&va;
      const u16* pb = (const u16*)&vb;
#pragma unroll
      for (int e = 0; e < 8; ++e)
        *(unsigned int*)(Vt + (vc + e) * 72 + vr) =
            (unsigned int)pa[e] | ((unsigned int)pb[e] << 16);
    }
    __syncthreads();

    if (jb < jbmax) {                      // prefetch next tile under compute
      const u16* kp = k + hs + (size_t)(jb + 64 + sr) * HS_ + sc;
      k0 = *(const uint4*)kp;
      k1 = *(const uint4*)(kp + 8);
      const u16* vp = v + hs + (size_t)(jb + 64 + vr) * HS_ + vc;
      va = *(const uint4*)vp;
      vb = *(const uint4*)(vp + HS_);
    }

#pragma unroll
    for (int u = 0; u < 2; ++u) {
      const int ru = (u ? qb1 : qb0) + w * 16;
      if (jb > ru + 15) continue;          // subtile fully above diagonal

      // Swapped QK^T: D[k-row = quad*4+r][q-col = col]
      f32x4 sacc[4] = {};
      __builtin_amdgcn_s_setprio(1);
#pragma unroll
      for (int ks = 0; ks < 2; ++ks)
#pragma unroll
        for (int t = 0; t < 4; ++t) {
          const bf16x8 kf = *(const bf16x8*)(Ks + (t * 16 + col) * 72 + ks * 32 + quad * 8);
          sacc[t] = __builtin_amdgcn_mfma_f32_16x16x32_bf16(kf, qf[u][ks], sacc[t], 0, 0, 0);
        }
      __builtin_amdgcn_s_setprio(0);

      if (jb + 63 > ru) {                  // diagonal tile: mask k > q
        const int q_l = ru + col;
#pragma unroll
        for (int t = 0; t < 4; ++t) {
          const int kb = jb + t * 16 + quad * 4;
#pragma unroll
          for (int r = 0; r < 4; ++r)
            if (kb + r > q_l) sacc[t][r] = -INFINITY;
        }
      }

      // Fixed-reference softmax: p = exp2(s) directly (|s| <~ 16; safe).
      float ls = 0.f;
#pragma unroll
      for (int t = 0; t < 4; ++t) {
        const float p0 = __builtin_amdgcn_exp2f(sacc[t][0]);
        const float p1 = __builtin_amdgcn_exp2f(sacc[t][1]);
        const float p2 = __builtin_amdgcn_exp2f(sacc[t][2]);
        const float p3 = __builtin_amdgcn_exp2f(sacc[t][3]);
        ls += (p0 + p1) + (p2 + p3);
        *(uint2*)(Ps[w] + col * 72 + t * 16 + quad * 4) =
            make_uint2(cvtpk(p0, p1), cvtpk(p2, p3));
      }
      l_run[u] += ls;

      __builtin_amdgcn_s_setprio(1);
#pragma unroll
      for (int ks = 0; ks < 2; ++ks) {
        const bf16x8 pf = *(const bf16x8*)(Ps[w] + col * 72 + ks * 32 + quad * 8);
#pragma unroll
        for (int nt = 0; nt < 4; ++nt) {
          const bf16x8 vf = *(const bf16x8*)(Vt + (nt * 16 + col) * 72 + ks * 32 + quad * 8);
          oacc[u][nt] = __builtin_amdgcn_mfma_f32_16x16x32_bf16(pf, vf, oacc[u][nt], 0, 0, 0);
        }
      }
      __builtin_amdgcn_s_setprio(0);
    }
  }

  u16* ob = o + (size_t)z * S_ * V_ + h * HS_;
#pragma unroll
  for (int u = 0; u < 2; ++u) {
    const int ru = (u ? qb1 : qb0) + w * 16;
    float lt = l_run[u];                   // reduce partials once
    lt += __shfl_xor(lt, 16);
    lt += __shfl_xor(lt, 32);
    float inv[4];
#pragma unroll
    for (int r = 0; r < 4; ++r) inv[r] = 1.0f / __shfl(lt, quad * 4 + r);
#pragma unroll
    for (int nt = 0; nt < 4; ++nt)
#pragma unroll
      for (int r = 0; r < 4; ++r)
        ob[(size_t)(ru + quad * 4 + r) * V_ + nt * 16 + col] = f2bf(oacc[u][nt][r] * inv[r]);
  }
}

// ---------------------------------------------------------------------------
// Output projection, MFMA NT-GEMM. R20: BK=64 (16 iterations, 32 MFMA/stage,
// half the barriers), reg-prefetch kept. LDS 2x128x72 u16 = 36.9KB.
// ---------------------------------------------------------------------------
__global__ __launch_bounds__(256) void oproj_mfma_kernel(
    const u16* __restrict__ a, const u16* __restrict__ bw, float* __restrict__ c)
{
  __shared__ __align__(16) u16 As[128 * 72];
  __shared__ __align__(16) u16 Bs[128 * 72];
  const int tid = threadIdx.x;
  const int m0 = blockIdx.x * 128;
  const int n0 = blockIdx.y * 128;
  const int w = tid >> 6, lane = tid & 63;
  const int col = lane & 15, quad = lane >> 4;
  const int qr = (w & 1) * 64;
  const int qc = (w >> 1) * 64;

  f32x4 acc[4][4] = {};

  const int sr = tid >> 2;            // 0..63
  const int sk = (tid & 3) * 16;      // 0,16,32,48 (u16 units)
  const u16* ga = a  + (size_t)(m0 + sr) * GK_ + sk;
  const u16* gb = bw + (size_t)(n0 + sr) * GK_ + sk;

  // prologue: stage k0 = 0 (rows sr and sr+64, 2 uint4 each per matrix)
  uint4 a0 = *(const uint4*)(ga);
  uint4 a1 = *(const uint4*)(ga + 8);
  uint4 a2 = *(const uint4*)(ga + (size_t)64 * GK_);
  uint4 a3 = *(const uint4*)(ga + (size_t)64 * GK_ + 8);
  uint4 b0 = *(const uint4*)(gb);
  uint4 b1 = *(const uint4*)(gb + 8);
  uint4 b2 = *(const uint4*)(gb + (size_t)64 * GK_);
  uint4 b3 = *(const uint4*)(gb + (size_t)64 * GK_ + 8);

  for (int k0 = 0; k0 < GK_; k0 += 64) {
    __syncthreads();                       // prev tile reads done
    *(uint4*)(As + sr * 72 + sk)            = a0;
    *(uint4*)(As + sr * 72 + sk + 8)        = a1;
    *(uint4*)(As + (64 + sr) * 72 + sk)     = a2;
    *(uint4*)(As + (64 + sr) * 72 + sk + 8) = a3;
    *(uint4*)(Bs + sr * 72 + sk)            = b0;
    *(uint4*)(Bs + sr * 72 + sk + 8)        = b1;
    *(uint4*)(Bs + (64 + sr) * 72 + sk)     = b2;
    *(uint4*)(Bs + (64 + sr) * 72 + sk + 8) = b3;
    __syncthreads();

    if (k0 + 64 < GK_) {                   // prefetch k+64 under compute
      a0 = *(const uint4*)(ga + k0 + 64);
      a1 = *(const uint4*)(ga + k0 + 64 + 8);
      a2 = *(const uint4*)(ga + (size_t)64 * GK_ + k0 + 64);
      a3 = *(const uint4*)(ga + (size_t)64 * GK_ + k0 + 64 + 8);
      b0 = *(const uint4*)(gb + k0 + 64);
      b1 = *(const uint4*)(gb + k0 + 64 + 8);
      b2 = *(const uint4*)(gb + (size_t)64 * GK_ + k0 + 64);
      b3 = *(const uint4*)(gb + (size_t)64 * GK_ + k0 + 64 + 8);
    }

#pragma unroll
    for (int ks = 0; ks < 2; ++ks) {
      bf16x8 af[4], bfr[4];
#pragma unroll
      for (int i = 0; i < 4; ++i) {
        af[i]  = *(const bf16x8*)(As + (qr + i * 16 + col) * 72 + ks * 32 + quad * 8);
        bfr[i] = *(const bf16x8*)(Bs + (qc + i * 16 + col) * 72 + ks * 32 + quad * 8);
      }
      __builtin_amdgcn_s_setprio(1);
#pragma unroll
      for (int i = 0; i < 4; ++i)
#pragma unroll
        for (int j = 0; j < 4; ++j)
          acc[i][j] = __builtin_amdgcn_mfma_f32_16x16x32_bf16(af[i], bfr[j], acc[i][j], 0, 0, 0);
      __builtin_amdgcn_s_setprio(0);
    }
  }

#pragma unroll
  for (int i = 0; i < 4; ++i)
#pragma unroll
    for (int j = 0; j < 4; ++j)
#pragma unroll
      for (int r = 0; r < 4; ++r)
        c[(size_t)(m0 + qr + i * 16 + quad * 4 + r) * GN_ + n0 + qc + j * 16 + col]
            = acc[i][j][r];
}

// ---------------------------------------------------------------------------
// Fallback vector oproj (per-batch mode only; unchanged).
// ---------------------------------------------------------------------------
__global__ __launch_bounds__(256) void oproj_vec_kernel(
    const u16* __restrict__ o, const void* __restrict__ w,
    float* __restrict__ out, const int* __restrict__ flag)
{
  __shared__ __align__(16) float At[64 * 68];
  __shared__ __align__(16) float Wt[64 * 68];
  const int tid = threadIdx.x;
  const size_t zo = (size_t)blockIdx.z * S_ * V_;
  const int m0 = blockIdx.x * 64;
  const int n0 = blockIdx.y * 64;
  const int tr = tid >> 4, tc = tid & 15;
  const int isf32 = *flag;
  const int srow = tid >> 2, sc = (tid & 3) * 16;

  float acc[4][4] = {};

  for (int k0 = 0; k0 < GK_; k0 += 64) {
    float av[16], wv[16];
    {
      const u16* gp = o + zo + (size_t)(m0 + srow) * GK_ + k0 + sc;
      uint4 u0 = *(const uint4*)gp;
      uint4 u1 = *(const uint4*)(gp + 8);
      av[0]=lo16(u0.x); av[1]=hi16(u0.x); av[2]=lo16(u0.y); av[3]=hi16(u0.y);
      av[4]=lo16(u0.z); av[5]=hi16(u0.z); av[6]=lo16(u0.w); av[7]=hi16(u0.w);
      av[8]=lo16(u1.x); av[9]=hi16(u1.x); av[10]=lo16(u1.y); av[11]=hi16(u1.y);
      av[12]=lo16(u1.z); av[13]=hi16(u1.z); av[14]=lo16(u1.w); av[15]=hi16(u1.w);
    }
    if (isf32) {
      const float4* gp = (const float4*)((const float*)w + (size_t)(n0 + srow) * GK_ + k0 + sc);
#pragma unroll
      for (int i = 0; i < 4; ++i) {
        float4 f = gp[i];
        wv[4*i+0]=f.x; wv[4*i+1]=f.y; wv[4*i+2]=f.z; wv[4*i+3]=f.w;
      }
    } else {
      const u16* gp = (const u16*)w + (size_t)(n0 + srow) * GK_ + k0 + sc;
      uint4 u0 = *(const uint4*)gp;
      uint4 u1 = *(const uint4*)(gp + 8);
      wv[0]=lo16(u0.x); wv[1]=hi16(u0.x); wv[2]=lo16(u0.y); wv[3]=hi16(u0.y);
      wv[4]=lo16(u0.z); wv[5]=hi16(u0.z); wv[6]=lo16(u0.w); wv[7]=hi16(u0.w);
      wv[8]=lo16(u1.x); wv[9]=hi16(u1.x); wv[10]=lo16(u1.y); wv[11]=hi16(u1.y);
      wv[12]=lo16(u1.z); wv[13]=hi16(u1.z); wv[14]=lo16(u1.w); wv[15]=hi16(u1.w);
    }
    __syncthreads();
#pragma unroll
    for (int i = 0; i < 16; ++i) {
      At[(sc + i) * 68 + srow] = av[i];
      Wt[(sc + i) * 68 + srow] = wv[i];
    }
    __syncthreads();

#pragma unroll 4
    for (int kk = 0; kk < 64; ++kk) {
      float4 a4 = *(const float4*)&At[kk * 68 + tr * 4];
      float4 w4 = *(const float4*)&Wt[kk * 68 + tc * 4];
      acc[0][0] += a4.x*w4.x; acc[0][1] += a4.x*w4.y; acc[0][2] += a4.x*w4.z; acc[0][3] += a4.x*w4.w;
      acc[1][0] += a4.y*w4.x; acc[1][1] += a4.y*w4.y; acc[1][2] += a4.y*w4.z; acc[1][3] += a4.y*w4.w;
      acc[2][0] += a4.z*w4.x; acc[2][1] += a4.z*w4.y; acc[2][2] += a4.z*w4.z; acc[2][3] += a4.z*w4.w;
      acc[3][0] += a4.w*w4.x; acc[3][1] += a4.w*w4.y; acc[3][2] += a4.w*w4.z; acc[3][3] += a4.w*w4.w;
    }
  }

#pragma unroll
  for (int r = 0; r < 4; ++r) {
    const int row = m0 + tr * 4 + r;
    *(float4*)(out + zo + (size_t)row * GN_ + n0 + tc * 4) =
        make_float4(acc[r][0], acc[r][1], acc[r][2], acc[r][3]);
  }
}

// ---------------------------------------------------------------------------
extern "C" void kernel_launch(void* const* d_in, const int* in_sizes, int n_in,
                              void* d_out, int out_size, void* d_ws, size_t ws_size,
                              hipStream_t stream) {
  const void* x = d_in[0];
  const void* wqkv = (n_in > 1) ? d_in[1] : d_in[0];
  const void* wout = (n_in > 2) ? d_in[2] : d_in[0];
  for (int i = 0; i < n_in; ++i) {
    if      (in_sizes[i] == B_ * S_ * V_)  x    = d_in[i];
    else if (in_sizes[i] == 3 * HS_ * HS_) wqkv = d_in[i];
    else if (in_sizes[i] == V_ * V_)       wout = d_in[i];
  }
  float* out = (float*)d_out;

  const size_t per_b = (size_t)H_ * S_ * HS_;
  const size_t SV = (size_t)S_ * V_;
  int* flag = (int*)d_ws;
  const bool full = ws_size >= (16 + 16 * per_b * sizeof(u16));
  const size_t stride = full ? 4 * per_b : per_b;
  u16* q = (u16*)((char*)d_ws + 16);
  u16* k = q + stride;
  u16* v = k + stride;
  u16* o = v + stride;

  detect_kernel<<<dim3(1), dim3(256), 0, stream>>>((const unsigned int*)x, flag);
  if (full) {
    qkv_mfma_kernel<<<dim3((B_ * S_ * H_) / 128), dim3(256), 0, stream>>>(
        x, wqkv, q, k, v, flag);
    attn_mfma_kernel<<<dim3(16, 16, B_), dim3(256), 0, stream>>>(q, k, v, o);
    u16* wb = q;   // q dead after attn
    wcvt_kernel<<<dim3((V_ * V_) / 1024), dim3(256), 0, stream>>>(wout, wb, flag);
    oproj_mfma_kernel<<<dim3((B_ * S_) / 128, GN_ / 128), dim3(256), 0, stream>>>(o, wb, out);
  } else {
    for (int b = 0; b < B_; ++b) {
      qkv_kernel<<<dim3(128, 1, 1), dim3(256), 0, stream>>>(x, b, wqkv, q, k, v, flag);
      attn_mfma_kernel<<<dim3(16, 16, 1), dim3(256), 0, stream>>>(q, k, v, o);
      oproj_vec_kernel<<<dim3(32, 16, 1), dim3(256), 0, stream>>>(
          o, wout, out + (size_t)b * SV, flag);
    }
  }
}

// Round 14
// 210.749 us; speedup vs baseline: 1.2674x; 1.0028x over previous
//
#include <hip/hip_runtime.h>

// Causal MHA. B=4, S=2048, V=1024, H=16, hs=64. Output fp32.
// R22: oproj rebuilt as 512-thread / 8-wave blocks, tile 128x128 kept,
// BK=64 kept, LDS 36.9KB kept, grid 512 kept -> waves/SIMD 2->4 with
// IDENTICAL data movement (isolates occupancy; R18's block-split was
// confounded). Wave w owns 64x32 quadrant: acc[4][2], 16 MFMA/iter.
// attn (R17 local optimum) + qkv (R21 swapped epilogue) unchanged.
#define B_  4
#define S_  2048
#define V_  1024
#define H_  16
#define HS_ 64
#define GK_ 1024
#define GN_ 1024

typedef unsigned short u16;
typedef __bf16 bf16x8 __attribute__((ext_vector_type(8)));
typedef float  f32x4  __attribute__((ext_vector_type(4)));

__device__ __forceinline__ float bf2f(u16 u) {
  return __uint_as_float(((unsigned int)u) << 16);
}
__device__ __forceinline__ float lo16(unsigned int w) { return __uint_as_float(w << 16); }
__device__ __forceinline__ float hi16(unsigned int w) { return __uint_as_float(w & 0xffff0000u); }
__device__ __forceinline__ u16 f2bf(float f) {
  unsigned int u = __float_as_uint(f);
  unsigned int r = u + 0x7fffu + ((u >> 16) & 1u);  // RNE
  return (u16)(r >> 16);
}
__device__ __forceinline__ unsigned int cvtpk(float lo, float hi) {
  unsigned int r;
  asm("v_cvt_pk_bf16_f32 %0, %1, %2" : "=v"(r) : "v"(lo), "v"(hi));
  return r;
}

// ---------------------------------------------------------------------------
// Input-storage detector (fp32 vs bf16; see R5/R7 notes).
// ---------------------------------------------------------------------------
__global__ __launch_bounds__(256) void detect_kernel(
    const unsigned int* __restrict__ x32, int* __restrict__ flag)
{
  __shared__ int zred[256];
  __shared__ int nred[256];
  const int tid = threadIdx.x;
  int nz = 0, nn = 0;
  for (int i = tid; i < 16384; i += 256) {
    unsigned int lo = x32[i] & 0xffffu;
    if (lo == 0u) nz++;
    if ((lo & 0x7f80u) == 0x7f80u && (lo & 0x7fu) != 0u) nn++;
  }
  zred[tid] = nz; nred[tid] = nn;
  __syncthreads();
  for (int s = 128; s > 0; s >>= 1) {
    if (tid < s) { zred[tid] += zred[tid + s]; nred[tid] += nred[tid + s]; }
    __syncthreads();
  }
  if (tid == 0) *flag = (zred[0] > 8192 || nred[0] > 0) ? 1 : 0;
}

// ---------------------------------------------------------------------------
// W_out -> bf16 (into q's dead workspace region, full mode only).
// ---------------------------------------------------------------------------
__global__ __launch_bounds__(256) void wcvt_kernel(
    const void* __restrict__ w, u16* __restrict__ wb, const int* __restrict__ flag)
{
  const int i = (blockIdx.x * 256 + threadIdx.x) * 4;
  if (*flag) {
    float4 f = *(const float4*)((const float*)w + i);
    unsigned int p0 = (unsigned int)f2bf(f.x) | ((unsigned int)f2bf(f.y) << 16);
    unsigned int p1 = (unsigned int)f2bf(f.z) | ((unsigned int)f2bf(f.w) << 16);
    *(uint2*)(wb + i) = make_uint2(p0, p1);
  } else {
    *(uint2*)(wb + i) = *(const uint2*)((const u16*)w + i);
  }
}

// ---------------------------------------------------------------------------
// MFMA QKV projection. C[m][e] = sum_d A[m][d] * W[e][d].
// R21: operand-swapped MFMA -> D[row=e(quad*4+r)][col=m(ar)]; epilogue
// packs 4 consecutive d per lane via cvtpk into uint2 stores.
// ---------------------------------------------------------------------------
__global__ __launch_bounds__(256) void qkv_mfma_kernel(
    const void* __restrict__ x, const void* __restrict__ wqkv,
    u16* __restrict__ q, u16* __restrict__ k, u16* __restrict__ v,
    const int* __restrict__ flag)
{
  __shared__ __align__(16) u16 Ws[192 * 80];   // 30720 B
  const int tid = threadIdx.x;
  const int isf32 = *flag;
  for (int idx = tid; idx < 192 * 4; idx += 256) {
    const int row = idx >> 2, c0 = (idx & 3) * 16;
    u16 t16[16];
    if (isf32) {
      const float4* gp = (const float4*)((const float*)wqkv + row * 64 + c0);
      float4 f0 = gp[0], f1 = gp[1], f2 = gp[2], f3 = gp[3];
      t16[0]=f2bf(f0.x); t16[1]=f2bf(f0.y); t16[2]=f2bf(f0.z); t16[3]=f2bf(f0.w);
      t16[4]=f2bf(f1.x); t16[5]=f2bf(f1.y); t16[6]=f2bf(f1.z); t16[7]=f2bf(f1.w);
      t16[8]=f2bf(f2.x); t16[9]=f2bf(f2.y); t16[10]=f2bf(f2.z); t16[11]=f2bf(f2.w);
      t16[12]=f2bf(f3.x); t16[13]=f2bf(f3.y); t16[14]=f2bf(f3.z); t16[15]=f2bf(f3.w);
    } else {
      const u16* gp = (const u16*)wqkv + row * 64 + c0;
      *(uint4*)t16 = *(const uint4*)gp;
      *(uint4*)(t16 + 8) = *(const uint4*)(gp + 8);
    }
    *(uint4*)(Ws + row * 80 + c0) = *(uint4*)t16;
    *(uint4*)(Ws + row * 80 + c0 + 8) = *(uint4*)(t16 + 8);
  }
  __syncthreads();

  const int m0 = blockIdx.x * 128;
  const int w = tid >> 6, lane = tid & 63;
  const int ar = lane & 15, quad = lane >> 4;
  const int rbase = m0 + (w & 1) * 64;     // wave rows (4 row-tiles)
  const int cbase = (w >> 1) * 96;         // wave cols (6 col-tiles)

  // A fragments direct from global: [m=ar][k=ks*32+quad*8+j]
  bf16x8 af[4][2];
#pragma unroll
  for (int rt = 0; rt < 4; ++rt) {
    const size_t row = (size_t)(rbase + rt * 16 + ar) * 64;
    if (isf32) {
      const float* gp = (const float*)x + row;
#pragma unroll
      for (int ks = 0; ks < 2; ++ks) {
        const float4* g4 = (const float4*)(gp + ks * 32 + quad * 8);
        float4 f0 = g4[0], f1 = g4[1];
        u16 t8[8];
        t8[0]=f2bf(f0.x); t8[1]=f2bf(f0.y); t8[2]=f2bf(f0.z); t8[3]=f2bf(f0.w);
        t8[4]=f2bf(f1.x); t8[5]=f2bf(f1.y); t8[6]=f2bf(f1.z); t8[7]=f2bf(f1.w);
        af[rt][ks] = *(bf16x8*)t8;
      }
    } else {
      const u16* gp = (const u16*)x + row;
#pragma unroll
      for (int ks = 0; ks < 2; ++ks)
        af[rt][ks] = *(const bf16x8*)(gp + ks * 32 + quad * 8);
    }
  }

  f32x4 acc[4][6] = {};
#pragma unroll
  for (int ks = 0; ks < 2; ++ks)
#pragma unroll
    for (int t = 0; t < 6; ++t) {
      const bf16x8 bfr = *(const bf16x8*)(Ws + (cbase + t * 16 + ar) * 80 + ks * 32 + quad * 8);
#pragma unroll
      for (int rt = 0; rt < 4; ++rt)
        acc[rt][t] = __builtin_amdgcn_mfma_f32_16x16x32_bf16(bfr, af[rt][ks], acc[rt][t], 0, 0, 0);
    }

  // epilogue (swapped layout): lane holds e = cbase+t*16+quad*4+r (r=0..3)
  // for row m = rbase + rt*16 + ar -> pack 4 consecutive d as uint2.
#pragma unroll
  for (int rt = 0; rt < 4; ++rt) {
    const int m = rbase + rt * 16 + ar;
    const int z = m >> 15, s = (m >> 4) & (S_ - 1), h = m & (H_ - 1);
    const size_t base = (((size_t)z * H_ + h) * S_ + s) * HS_;
#pragma unroll
    for (int t = 0; t < 6; ++t) {
      const int e0 = cbase + t * 16 + quad * 4;
      u16* dst = (e0 < 64) ? q : (e0 < 128) ? k : v;
      const unsigned int w0 = cvtpk(acc[rt][t][0], acc[rt][t][1]);
      const unsigned int w1 = cvtpk(acc[rt][t][2], acc[rt][t][3]);
      *(uint2*)(dst + base + (e0 & 63)) = make_uint2(w0, w1);
    }
  }
}

// ---------------------------------------------------------------------------
// Fallback vector QKV (per-batch mode only; unchanged from R9).
// ---------------------------------------------------------------------------
__global__ __launch_bounds__(256) void qkv_kernel(
    const void* __restrict__ x, int b0, const void* __restrict__ w,
    u16* __restrict__ q, u16* __restrict__ k, u16* __restrict__ v,
    const int* __restrict__ flag)
{
  __shared__ __align__(16) float Ws[192 * 64];
  const int tid = threadIdx.x;
  const int isf32 = *flag;
  if (isf32) {
    for (int i = tid; i < 192 * 64; i += 256) Ws[i] = ((const float*)w)[i];
  } else {
    for (int i = tid; i < 192 * 64; i += 256) Ws[i] = bf2f(((const u16*)w)[i]);
  }
  __syncthreads();

  const int th = blockIdx.x * 256 + tid;
  const int h = th & (H_ - 1);
  const int s = th >> 4;
  const int b = b0 + blockIdx.z;
  const size_t zoff = (size_t)blockIdx.z * H_ * S_ * HS_;
  const size_t xoff = ((size_t)b * S_ + s) * V_ + h * HS_;

  float xf[64];
  if (isf32) {
    const float4* xp = (const float4*)((const float*)x + xoff);
#pragma unroll
    for (int i = 0; i < 16; ++i) {
      float4 u = xp[i];
      xf[4*i+0] = u.x; xf[4*i+1] = u.y; xf[4*i+2] = u.z; xf[4*i+3] = u.w;
    }
  } else {
    const uint4* xp = (const uint4*)((const u16*)x + xoff);
#pragma unroll
    for (int i = 0; i < 8; ++i) {
      uint4 u = xp[i];
      xf[8*i+0] = lo16(u.x); xf[8*i+1] = hi16(u.x);
      xf[8*i+2] = lo16(u.y); xf[8*i+3] = hi16(u.y);
      xf[8*i+4] = lo16(u.z); xf[8*i+5] = hi16(u.z);
      xf[8*i+6] = lo16(u.w); xf[8*i+7] = hi16(u.w);
    }
  }

  const size_t obase = zoff + ((size_t)h * S_ + s) * HS_;
#pragma unroll 1
  for (int eg = 0; eg < 12; ++eg) {
    float acc[16];
#pragma unroll
    for (int ee = 0; ee < 16; ++ee) {
      const float4* wr = (const float4*)&Ws[(eg * 16 + ee) * 64];
      float a = 0.f;
#pragma unroll
      for (int d4 = 0; d4 < 16; ++d4) {
        float4 wv = wr[d4];
        a += xf[d4*4+0]*wv.x + xf[d4*4+1]*wv.y + xf[d4*4+2]*wv.z + xf[d4*4+3]*wv.w;
      }
      acc[ee] = a;
    }
    u16* dst = (eg < 4) ? q : (eg < 8) ? k : v;
    const int d0 = (eg & 3) * 16;
    unsigned int p[8];
#pragma unroll
    for (int t = 0; t < 8; ++t)
      p[t] = (unsigned int)f2bf(acc[2*t]) | ((unsigned int)f2bf(acc[2*t+1]) << 16);
    uint4* dp = (uint4*)(dst + obase + d0);
    dp[0] = make_uint4(p[0], p[1], p[2], p[3]);
    dp[1] = make_uint4(p[4], p[5], p[6], p[7]);
  }
}

// ---------------------------------------------------------------------------
// R17 MFMA flash attention (local optimum, 74.5us). Block = 4 waves; block i
// owns strips i (u0) and 31-i (u1) -> uniform 33 tile-units/wave. Swapped
// QK^T D[k=quad*4+r][q=col]. Fixed-reference softmax: p = exp2(s) directly.
// P packed via cvt_pk; l partials reduced in epilogue.
// ---------------------------------------------------------------------------
__global__ __launch_bounds__(256, 4) void attn_mfma_kernel(
    const u16* __restrict__ q, const u16* __restrict__ k,
    const u16* __restrict__ v, u16* __restrict__ o)
{
  const int z   = blockIdx.z;
  const int h   = blockIdx.y;
  const int bi  = blockIdx.x;          // 0..15
  const int qb0 = bi * 64;             // top subtile (u=0)
  const int qb1 = (31 - bi) * 64;      // bottom subtile (u=1)
  const int tid = threadIdx.x;
  const int w = tid >> 6, lane = tid & 63;
  const int col = lane & 15, quad = lane >> 4;

  __shared__ __align__(16) u16 Ks[64 * 72];
  __shared__ __align__(16) u16 Vt[64 * 72];
  __shared__ __align__(16) u16 Ps[4][16 * 72];

  const size_t hs = ((size_t)z * H_ + h) * S_ * HS_;

  // Q fragments for the two subtiles; scale folds 1/8 and log2(e).
  const float qs = 0.125f * 1.44269504089f;
  bf16x8 qf[2][2];
#pragma unroll
  for (int u = 0; u < 2; ++u) {
    const int qb = u ? qb1 : qb0;
    const u16* qp = q + hs + (size_t)(qb + w * 16 + col) * HS_ + quad * 8;
#pragma unroll
    for (int ks = 0; ks < 2; ++ks) {
      u16 t8[8];
      *(uint4*)t8 = *(const uint4*)(qp + ks * 32);
#pragma unroll
      for (int e = 0; e < 8; ++e) t8[e] = f2bf(bf2f(t8[e]) * qs);
      qf[u][ks] = *(bf16x8*)t8;
    }
  }

  const int sr = tid >> 2, sc = (tid & 3) * 16;        // K staging: 64x64
  const int vr = (tid & 31) * 2, vc = (tid >> 5) * 8;  // V staging: 2 rows x 8 cols

  f32x4 oacc[2][4] = {};
  float l_run[2] = {0.f, 0.f};         // per-lane PARTIAL row sums

  const int jbmax = qb1;               // bottom subtile's diagonal tile

  // prologue: load tile 0
  uint4 k0, k1, va, vb;
  {
    const u16* kp = k + hs + (size_t)sr * HS_ + sc;
    k0 = *(const uint4*)kp;
    k1 = *(const uint4*)(kp + 8);
    const u16* vp = v + hs + (size_t)vr * HS_ + vc;
    va = *(const uint4*)vp;
    vb = *(const uint4*)(vp + HS_);
  }

  for (int jb = 0; jb <= jbmax; jb += 64) {
    __syncthreads();                       // all waves done reading prev tile
    *(uint4*)(Ks + sr * 72 + sc)     = k0;
    *(uint4*)(Ks + sr * 72 + sc + 8) = k1;
    {
      const u16* pa = (const u16*)&va;
      const u16* pb = (const u16*)&vb;
#pragma unroll
      for (int e = 0; e < 8; ++e)
        *(unsigned int*)(Vt + (vc + e) * 72 + vr) =
            (unsigned int)pa[e] | ((unsigned int)pb[e] << 16);
    }
    __syncthreads();

    if (jb < jbmax) {                      // prefetch next tile under compute
      const u16* kp = k + hs + (size_t)(jb + 64 + sr) * HS_ + sc;
      k0 = *(const uint4*)kp;
      k1 = *(const uint4*)(kp + 8);
      const u16* vp = v + hs + (size_t)(jb + 64 + vr) * HS_ + vc;
      va = *(const uint4*)vp;
      vb = *(const uint4*)(vp + HS_);
    }

#pragma unroll
    for (int u = 0; u < 2; ++u) {
      const int ru = (u ? qb1 : qb0) + w * 16;
      if (jb > ru + 15) continue;          // subtile fully above diagonal

      // Swapped QK^T: D[k-row = quad*4+r][q-col = col]
      f32x4 sacc[4] = {};
      __builtin_amdgcn_s_setprio(1);
#pragma unroll
      for (int ks = 0; ks < 2; ++ks)
#pragma unroll
        for (int t = 0; t < 4; ++t) {
          const bf16x8 kf = *(const bf16x8*)(Ks + (t * 16 + col) * 72 + ks * 32 + quad * 8);
          sacc[t] = __builtin_amdgcn_mfma_f32_16x16x32_bf16(kf, qf[u][ks], sacc[t], 0, 0, 0);
        }
      __builtin_amdgcn_s_setprio(0);

      if (jb + 63 > ru) {                  // diagonal tile: mask k > q
        const int q_l = ru + col;
#pragma unroll
        for (int t = 0; t < 4; ++t) {
          const int kb = jb + t * 16 + quad * 4;
#pragma unroll
          for (int r = 0; r < 4; ++r)
            if (kb + r > q_l) sacc[t][r] = -INFINITY;
        }
      }

      // Fixed-reference softmax: p = exp2(s) directly (|s| <~ 16; safe).
      float ls = 0.f;
#pragma unroll
      for (int t = 0; t < 4; ++t) {
        const float p0 = __builtin_amdgcn_exp2f(sacc[t][0]);
        const float p1 = __builtin_amdgcn_exp2f(sacc[t][1]);
        const float p2 = __builtin_amdgcn_exp2f(sacc[t][2]);
        const float p3 = __builtin_amdgcn_exp2f(sacc[t][3]);
        ls += (p0 + p1) + (p2 + p3);
        *(uint2*)(Ps[w] + col * 72 + t * 16 + quad * 4) =
            make_uint2(cvtpk(p0, p1), cvtpk(p2, p3));
      }
      l_run[u] += ls;

      __builtin_amdgcn_s_setprio(1);
#pragma unroll
      for (int ks = 0; ks < 2; ++ks) {
        const bf16x8 pf = *(const bf16x8*)(Ps[w] + col * 72 + ks * 32 + quad * 8);
#pragma unroll
        for (int nt = 0; nt < 4; ++nt) {
          const bf16x8 vf = *(const bf16x8*)(Vt + (nt * 16 + col) * 72 + ks * 32 + quad * 8);
          oacc[u][nt] = __builtin_amdgcn_mfma_f32_16x16x32_bf16(pf, vf, oacc[u][nt], 0, 0, 0);
        }
      }
      __builtin_amdgcn_s_setprio(0);
    }
  }

  u16* ob = o + (size_t)z * S_ * V_ + h * HS_;
#pragma unroll
  for (int u = 0; u < 2; ++u) {
    const int ru = (u ? qb1 : qb0) + w * 16;
    float lt = l_run[u];                   // reduce partials once
    lt += __shfl_xor(lt, 16);
    lt += __shfl_xor(lt, 32);
    float inv[4];
#pragma unroll
    for (int r = 0; r < 4; ++r) inv[r] = 1.0f / __shfl(lt, quad * 4 + r);
#pragma unroll
    for (int nt = 0; nt < 4; ++nt)
#pragma unroll
      for (int r = 0; r < 4; ++r)
        ob[(size_t)(ru + quad * 4 + r) * V_ + nt * 16 + col] = f2bf(oacc[u][nt][r] * inv[r]);
  }
}

// ---------------------------------------------------------------------------
// Output projection, MFMA NT-GEMM. R22: 512 threads / 8 waves per block,
// tile 128x128, BK=64, reg-prefetch. Wave w owns 64x32 quadrant
// (qr=(w&1)*64, qc=(w>>1)*32): acc[4][2], 16 MFMA/iter. Same grid and LDS
// as R20 -> identical data movement, 2x waves/SIMD (2->4).
// ---------------------------------------------------------------------------
__global__ __launch_bounds__(512) void oproj_mfma_kernel(
    const u16* __restrict__ a, const u16* __restrict__ bw, float* __restrict__ c)
{
  __shared__ __align__(16) u16 As[128 * 72];
  __shared__ __align__(16) u16 Bs[128 * 72];
  const int tid = threadIdx.x;        // 0..511
  const int m0 = blockIdx.x * 128;
  const int n0 = blockIdx.y * 128;
  const int w = tid >> 6, lane = tid & 63;
  const int col = lane & 15, quad = lane >> 4;
  const int qr = (w & 1) * 64;        // row half
  const int qc = (w >> 1) * 32;       // col strip

  f32x4 acc[4][2] = {};

  const int sr = tid >> 2;            // 0..127 (all rows)
  const int sk = (tid & 3) * 16;      // 0,16,32,48 (u16 units)
  const u16* ga = a  + (size_t)(m0 + sr) * GK_ + sk;
  const u16* gb = bw + (size_t)(n0 + sr) * GK_ + sk;

  // prologue: stage k0 = 0 (2 uint4 per matrix per thread)
  uint4 a0 = *(const uint4*)(ga);
  uint4 a1 = *(const uint4*)(ga + 8);
  uint4 b0 = *(const uint4*)(gb);
  uint4 b1 = *(const uint4*)(gb + 8);

  for (int k0 = 0; k0 < GK_; k0 += 64) {
    __syncthreads();                       // prev tile reads done
    *(uint4*)(As + sr * 72 + sk)     = a0;
    *(uint4*)(As + sr * 72 + sk + 8) = a1;
    *(uint4*)(Bs + sr * 72 + sk)     = b0;
    *(uint4*)(Bs + sr * 72 + sk + 8) = b1;
    __syncthreads();

    if (k0 + 64 < GK_) {                   // prefetch k+64 under compute
      a0 = *(const uint4*)(ga + k0 + 64);
      a1 = *(const uint4*)(ga + k0 + 64 + 8);
      b0 = *(const uint4*)(gb + k0 + 64);
      b1 = *(const uint4*)(gb + k0 + 64 + 8);
    }

#pragma unroll
    for (int ks = 0; ks < 2; ++ks) {
      bf16x8 af[4], bfr[2];
#pragma unroll
      for (int i = 0; i < 4; ++i)
        af[i] = *(const bf16x8*)(As + (qr + i * 16 + col) * 72 + ks * 32 + quad * 8);
#pragma unroll
      for (int j = 0; j < 2; ++j)
        bfr[j] = *(const bf16x8*)(Bs + (qc + j * 16 + col) * 72 + ks * 32 + quad * 8);
      __builtin_amdgcn_s_setprio(1);
#pragma unroll
      for (int i = 0; i < 4; ++i)
#pragma unroll
        for (int j = 0; j < 2; ++j)
          acc[i][j] = __builtin_amdgcn_mfma_f32_16x16x32_bf16(af[i], bfr[j], acc[i][j], 0, 0, 0);
      __builtin_amdgcn_s_setprio(0);
    }
  }

#pragma unroll
  for (int i = 0; i < 4; ++i)
#pragma unroll
    for (int j = 0; j < 2; ++j)
#pragma unroll
      for (int r = 0; r < 4; ++r)
        c[(size_t)(m0 + qr + i * 16 + quad * 4 + r) * GN_ + n0 + qc + j * 16 + col]
            = acc[i][j][r];
}

// ---------------------------------------------------------------------------
// Fallback vector oproj (per-batch mode only; unchanged).
// ---------------------------------------------------------------------------
__global__ __launch_bounds__(256) void oproj_vec_kernel(
    const u16* __restrict__ o, const void* __restrict__ w,
    float* __restrict__ out, const int* __restrict__ flag)
{
  __shared__ __align__(16) float At[64 * 68];
  __shared__ __align__(16) float Wt[64 * 68];
  const int tid = threadIdx.x;
  const size_t zo = (size_t)blockIdx.z * S_ * V_;
  const int m0 = blockIdx.x * 64;
  const int n0 = blockIdx.y * 64;
  const int tr = tid >> 4, tc = tid & 15;
  const int isf32 = *flag;
  const int srow = tid >> 2, sc = (tid & 3) * 16;

  float acc[4][4] = {};

  for (int k0 = 0; k0 < GK_; k0 += 64) {
    float av[16], wv[16];
    {
      const u16* gp = o + zo + (size_t)(m0 + srow) * GK_ + k0 + sc;
      uint4 u0 = *(const uint4*)gp;
      uint4 u1 = *(const uint4*)(gp + 8);
      av[0]=lo16(u0.x); av[1]=hi16(u0.x); av[2]=lo16(u0.y); av[3]=hi16(u0.y);
      av[4]=lo16(u0.z); av[5]=hi16(u0.z); av[6]=lo16(u0.w); av[7]=hi16(u0.w);
      av[8]=lo16(u1.x); av[9]=hi16(u1.x); av[10]=lo16(u1.y); av[11]=hi16(u1.y);
      av[12]=lo16(u1.z); av[13]=hi16(u1.z); av[14]=lo16(u1.w); av[15]=hi16(u1.w);
    }
    if (isf32) {
      const float4* gp = (const float4*)((const float*)w + (size_t)(n0 + srow) * GK_ + k0 + sc);
#pragma unroll
      for (int i = 0; i < 4; ++i) {
        float4 f = gp[i];
        wv[4*i+0]=f.x; wv[4*i+1]=f.y; wv[4*i+2]=f.z; wv[4*i+3]=f.w;
      }
    } else {
      const u16* gp = (const u16*)w + (size_t)(n0 + srow) * GK_ + k0 + sc;
      uint4 u0 = *(const uint4*)gp;
      uint4 u1 = *(const uint4*)(gp + 8);
      wv[0]=lo16(u0.x); wv[1]=hi16(u0.x); wv[2]=lo16(u0.y); wv[3]=hi16(u0.y);
      wv[4]=lo16(u0.z); wv[5]=hi16(u0.z); wv[6]=lo16(u0.w); wv[7]=hi16(u0.w);
      wv[8]=lo16(u1.x); wv[9]=hi16(u1.x); wv[10]=lo16(u1.y); wv[11]=hi16(u1.y);
      wv[12]=lo16(u1.z); wv[13]=hi16(u1.z); wv[14]=lo16(u1.w); wv[15]=hi16(u1.w);
    }
    __syncthreads();
#pragma unroll
    for (int i = 0; i < 16; ++i) {
      At[(sc + i) * 68 + srow] = av[i];
      Wt[(sc + i) * 68 + srow] = wv[i];
    }
    __syncthreads();

#pragma unroll 4
    for (int kk = 0; kk < 64; ++kk) {
      float4 a4 = *(const float4*)&At[kk * 68 + tr * 4];
      float4 w4 = *(const float4*)&Wt[kk * 68 + tc * 4];
      acc[0][0] += a4.x*w4.x; acc[0][1] += a4.x*w4.y; acc[0][2] += a4.x*w4.z; acc[0][3] += a4.x*w4.w;
      acc[1][0] += a4.y*w4.x; acc[1][1] += a4.y*w4.y; acc[1][2] += a4.y*w4.z; acc[1][3] += a4.y*w4.w;
      acc[2][0] += a4.z*w4.x; acc[2][1] += a4.z*w4.y; acc[2][2] += a4.z*w4.z; acc[2][3] += a4.z*w4.w;
      acc[3][0] += a4.w*w4.x; acc[3][1] += a4.w*w4.y; acc[3][2] += a4.w*w4.z; acc[3][3] += a4.w*w4.w;
    }
  }

#pragma unroll
  for (int r = 0; r < 4; ++r) {
    const int row = m0 + tr * 4 + r;
    *(float4*)(out + zo + (size_t)row * GN_ + n0 + tc * 4) =
        make_float4(acc[r][0], acc[r][1], acc[r][2], acc[r][3]);
  }
}

// ---------------------------------------------------------------------------
extern "C" void kernel_launch(void* const* d_in, const int* in_sizes, int n_in,
                              void* d_out, int out_size, void* d_ws, size_t ws_size,
                              hipStream_t stream) {
  const void* x = d_in[0];
  const void* wqkv = (n_in > 1) ? d_in[1] : d_in[0];
  const void* wout = (n_in > 2) ? d_in[2] : d_in[0];
  for (int i = 0; i < n_in; ++i) {
    if      (in_sizes[i] == B_ * S_ * V_)  x    = d_in[i];
    else if (in_sizes[i] == 3 * HS_ * HS_) wqkv = d_in[i];
    else if (in_sizes[i] == V_ * V_)       wout = d_in[i];
  }
  float* out = (float*)d_out;

  const size_t per_b = (size_t)H_ * S_ * HS_;
  const size_t SV = (size_t)S_ * V_;
  int* flag = (int*)d_ws;
  const bool full = ws_size >= (16 + 16 * per_b * sizeof(u16));
  const size_t stride = full ? 4 * per_b : per_b;
  u16* q = (u16*)((char*)d_ws + 16);
  u16* k = q + stride;
  u16* v = k + stride;
  u16* o = v + stride;

  detect_kernel<<<dim3(1), dim3(256), 0, stream>>>((const unsigned int*)x, flag);
  if (full) {
    qkv_mfma_kernel<<<dim3((B_ * S_ * H_) / 128), dim3(256), 0, stream>>>(
        x, wqkv, q, k, v, flag);
    attn_mfma_kernel<<<dim3(16, 16, B_), dim3(256), 0, stream>>>(q, k, v, o);
    u16* wb = q;   // q dead after attn
    wcvt_kernel<<<dim3((V_ * V_) / 1024), dim3(256), 0, stream>>>(wout, wb, flag);
    oproj_mfma_kernel<<<dim3((B_ * S_) / 128, GN_ / 128), dim3(512), 0, stream>>>(o, wb, out);
  } else {
    for (int b = 0; b < B_; ++b) {
      qkv_kernel<<<dim3(128, 1, 1), dim3(256), 0, stream>>>(x, b, wqkv, q, k, v, flag);
      attn_mfma_kernel<<<dim3(16, 16, 1), dim3(256), 0, stream>>>(q, k, v, o);
      oproj_vec_kernel<<<dim3(32, 16, 1), dim3(256), 0, stream>>>(
          o, wout, out + (size_t)b * SV, flag);
    }
  }
}

// Round 15
// 206.243 us; speedup vs baseline: 1.2951x; 1.0219x over previous
//
#include <hip/hip_runtime.h>

// Causal MHA. B=4, S=2048, V=1024, H=16, hs=64. Output fp32.
// R23: attn XCD-chunked block swizzle (T1). Grid (16,16,4) flattened
// x-fastest put the 16 blocks sharing a KV panel round-robin across all
// 8 XCDs -> each XCD L2 fetched the same panel (FETCH 162MB vs 33.6MB
// ideal, 5x). Bijective remap wid=(bid&7)*128+(bid>>3): each XCD serves
// 8 complete (h,z) panels = 4MB KV = its L2 size. Pure index remap.
// attn body (R17 optimum), qkv (R21), oproj (R22 8-wave) unchanged.
#define B_  4
#define S_  2048
#define V_  1024
#define H_  16
#define HS_ 64
#define GK_ 1024
#define GN_ 1024

typedef unsigned short u16;
typedef __bf16 bf16x8 __attribute__((ext_vector_type(8)));
typedef float  f32x4  __attribute__((ext_vector_type(4)));

__device__ __forceinline__ float bf2f(u16 u) {
  return __uint_as_float(((unsigned int)u) << 16);
}
__device__ __forceinline__ float lo16(unsigned int w) { return __uint_as_float(w << 16); }
__device__ __forceinline__ float hi16(unsigned int w) { return __uint_as_float(w & 0xffff0000u); }
__device__ __forceinline__ u16 f2bf(float f) {
  unsigned int u = __float_as_uint(f);
  unsigned int r = u + 0x7fffu + ((u >> 16) & 1u);  // RNE
  return (u16)(r >> 16);
}
__device__ __forceinline__ unsigned int cvtpk(float lo, float hi) {
  unsigned int r;
  asm("v_cvt_pk_bf16_f32 %0, %1, %2" : "=v"(r) : "v"(lo), "v"(hi));
  return r;
}

// ---------------------------------------------------------------------------
// Input-storage detector (fp32 vs bf16; see R5/R7 notes).
// ---------------------------------------------------------------------------
__global__ __launch_bounds__(256) void detect_kernel(
    const unsigned int* __restrict__ x32, int* __restrict__ flag)
{
  __shared__ int zred[256];
  __shared__ int nred[256];
  const int tid = threadIdx.x;
  int nz = 0, nn = 0;
  for (int i = tid; i < 16384; i += 256) {
    unsigned int lo = x32[i] & 0xffffu;
    if (lo == 0u) nz++;
    if ((lo & 0x7f80u) == 0x7f80u && (lo & 0x7fu) != 0u) nn++;
  }
  zred[tid] = nz; nred[tid] = nn;
  __syncthreads();
  for (int s = 128; s > 0; s >>= 1) {
    if (tid < s) { zred[tid] += zred[tid + s]; nred[tid] += nred[tid + s]; }
    __syncthreads();
  }
  if (tid == 0) *flag = (zred[0] > 8192 || nred[0] > 0) ? 1 : 0;
}

// ---------------------------------------------------------------------------
// W_out -> bf16 (into q's dead workspace region, full mode only).
// ---------------------------------------------------------------------------
__global__ __launch_bounds__(256) void wcvt_kernel(
    const void* __restrict__ w, u16* __restrict__ wb, const int* __restrict__ flag)
{
  const int i = (blockIdx.x * 256 + threadIdx.x) * 4;
  if (*flag) {
    float4 f = *(const float4*)((const float*)w + i);
    unsigned int p0 = (unsigned int)f2bf(f.x) | ((unsigned int)f2bf(f.y) << 16);
    unsigned int p1 = (unsigned int)f2bf(f.z) | ((unsigned int)f2bf(f.w) << 16);
    *(uint2*)(wb + i) = make_uint2(p0, p1);
  } else {
    *(uint2*)(wb + i) = *(const uint2*)((const u16*)w + i);
  }
}

// ---------------------------------------------------------------------------
// MFMA QKV projection. C[m][e] = sum_d A[m][d] * W[e][d].
// R21: operand-swapped MFMA -> D[row=e(quad*4+r)][col=m(ar)]; epilogue
// packs 4 consecutive d per lane via cvtpk into uint2 stores.
// ---------------------------------------------------------------------------
__global__ __launch_bounds__(256) void qkv_mfma_kernel(
    const void* __restrict__ x, const void* __restrict__ wqkv,
    u16* __restrict__ q, u16* __restrict__ k, u16* __restrict__ v,
    const int* __restrict__ flag)
{
  __shared__ __align__(16) u16 Ws[192 * 80];   // 30720 B
  const int tid = threadIdx.x;
  const int isf32 = *flag;
  for (int idx = tid; idx < 192 * 4; idx += 256) {
    const int row = idx >> 2, c0 = (idx & 3) * 16;
    u16 t16[16];
    if (isf32) {
      const float4* gp = (const float4*)((const float*)wqkv + row * 64 + c0);
      float4 f0 = gp[0], f1 = gp[1], f2 = gp[2], f3 = gp[3];
      t16[0]=f2bf(f0.x); t16[1]=f2bf(f0.y); t16[2]=f2bf(f0.z); t16[3]=f2bf(f0.w);
      t16[4]=f2bf(f1.x); t16[5]=f2bf(f1.y); t16[6]=f2bf(f1.z); t16[7]=f2bf(f1.w);
      t16[8]=f2bf(f2.x); t16[9]=f2bf(f2.y); t16[10]=f2bf(f2.z); t16[11]=f2bf(f2.w);
      t16[12]=f2bf(f3.x); t16[13]=f2bf(f3.y); t16[14]=f2bf(f3.z); t16[15]=f2bf(f3.w);
    } else {
      const u16* gp = (const u16*)wqkv + row * 64 + c0;
      *(uint4*)t16 = *(const uint4*)gp;
      *(uint4*)(t16 + 8) = *(const uint4*)(gp + 8);
    }
    *(uint4*)(Ws + row * 80 + c0) = *(uint4*)t16;
    *(uint4*)(Ws + row * 80 + c0 + 8) = *(uint4*)(t16 + 8);
  }
  __syncthreads();

  const int m0 = blockIdx.x * 128;
  const int w = tid >> 6, lane = tid & 63;
  const int ar = lane & 15, quad = lane >> 4;
  const int rbase = m0 + (w & 1) * 64;     // wave rows (4 row-tiles)
  const int cbase = (w >> 1) * 96;         // wave cols (6 col-tiles)

  // A fragments direct from global: [m=ar][k=ks*32+quad*8+j]
  bf16x8 af[4][2];
#pragma unroll
  for (int rt = 0; rt < 4; ++rt) {
    const size_t row = (size_t)(rbase + rt * 16 + ar) * 64;
    if (isf32) {
      const float* gp = (const float*)x + row;
#pragma unroll
      for (int ks = 0; ks < 2; ++ks) {
        const float4* g4 = (const float4*)(gp + ks * 32 + quad * 8);
        float4 f0 = g4[0], f1 = g4[1];
        u16 t8[8];
        t8[0]=f2bf(f0.x); t8[1]=f2bf(f0.y); t8[2]=f2bf(f0.z); t8[3]=f2bf(f0.w);
        t8[4]=f2bf(f1.x); t8[5]=f2bf(f1.y); t8[6]=f2bf(f1.z); t8[7]=f2bf(f1.w);
        af[rt][ks] = *(bf16x8*)t8;
      }
    } else {
      const u16* gp = (const u16*)x + row;
#pragma unroll
      for (int ks = 0; ks < 2; ++ks)
        af[rt][ks] = *(const bf16x8*)(gp + ks * 32 + quad * 8);
    }
  }

  f32x4 acc[4][6] = {};
#pragma unroll
  for (int ks = 0; ks < 2; ++ks)
#pragma unroll
    for (int t = 0; t < 6; ++t) {
      const bf16x8 bfr = *(const bf16x8*)(Ws + (cbase + t * 16 + ar) * 80 + ks * 32 + quad * 8);
#pragma unroll
      for (int rt = 0; rt < 4; ++rt)
        acc[rt][t] = __builtin_amdgcn_mfma_f32_16x16x32_bf16(bfr, af[rt][ks], acc[rt][t], 0, 0, 0);
    }

  // epilogue (swapped layout): lane holds e = cbase+t*16+quad*4+r (r=0..3)
  // for row m = rbase + rt*16 + ar -> pack 4 consecutive d as uint2.
#pragma unroll
  for (int rt = 0; rt < 4; ++rt) {
    const int m = rbase + rt * 16 + ar;
    const int z = m >> 15, s = (m >> 4) & (S_ - 1), h = m & (H_ - 1);
    const size_t base = (((size_t)z * H_ + h) * S_ + s) * HS_;
#pragma unroll
    for (int t = 0; t < 6; ++t) {
      const int e0 = cbase + t * 16 + quad * 4;
      u16* dst = (e0 < 64) ? q : (e0 < 128) ? k : v;
      const unsigned int w0 = cvtpk(acc[rt][t][0], acc[rt][t][1]);
      const unsigned int w1 = cvtpk(acc[rt][t][2], acc[rt][t][3]);
      *(uint2*)(dst + base + (e0 & 63)) = make_uint2(w0, w1);
    }
  }
}

// ---------------------------------------------------------------------------
// Fallback vector QKV (per-batch mode only; unchanged from R9).
// ---------------------------------------------------------------------------
__global__ __launch_bounds__(256) void qkv_kernel(
    const void* __restrict__ x, int b0, const void* __restrict__ w,
    u16* __restrict__ q, u16* __restrict__ k, u16* __restrict__ v,
    const int* __restrict__ flag)
{
  __shared__ __align__(16) float Ws[192 * 64];
  const int tid = threadIdx.x;
  const int isf32 = *flag;
  if (isf32) {
    for (int i = tid; i < 192 * 64; i += 256) Ws[i] = ((const float*)w)[i];
  } else {
    for (int i = tid; i < 192 * 64; i += 256) Ws[i] = bf2f(((const u16*)w)[i]);
  }
  __syncthreads();

  const int th = blockIdx.x * 256 + tid;
  const int h = th & (H_ - 1);
  const int s = th >> 4;
  const int b = b0 + blockIdx.z;
  const size_t zoff = (size_t)blockIdx.z * H_ * S_ * HS_;
  const size_t xoff = ((size_t)b * S_ + s) * V_ + h * HS_;

  float xf[64];
  if (isf32) {
    const float4* xp = (const float4*)((const float*)x + xoff);
#pragma unroll
    for (int i = 0; i < 16; ++i) {
      float4 u = xp[i];
      xf[4*i+0] = u.x; xf[4*i+1] = u.y; xf[4*i+2] = u.z; xf[4*i+3] = u.w;
    }
  } else {
    const uint4* xp = (const uint4*)((const u16*)x + xoff);
#pragma unroll
    for (int i = 0; i < 8; ++i) {
      uint4 u = xp[i];
      xf[8*i+0] = lo16(u.x); xf[8*i+1] = hi16(u.x);
      xf[8*i+2] = lo16(u.y); xf[8*i+3] = hi16(u.y);
      xf[8*i+4] = lo16(u.z); xf[8*i+5] = hi16(u.z);
      xf[8*i+6] = lo16(u.w); xf[8*i+7] = hi16(u.w);
    }
  }

  const size_t obase = zoff + ((size_t)h * S_ + s) * HS_;
#pragma unroll 1
  for (int eg = 0; eg < 12; ++eg) {
    float acc[16];
#pragma unroll
    for (int ee = 0; ee < 16; ++ee) {
      const float4* wr = (const float4*)&Ws[(eg * 16 + ee) * 64];
      float a = 0.f;
#pragma unroll
      for (int d4 = 0; d4 < 16; ++d4) {
        float4 wv = wr[d4];
        a += xf[d4*4+0]*wv.x + xf[d4*4+1]*wv.y + xf[d4*4+2]*wv.z + xf[d4*4+3]*wv.w;
      }
      acc[ee] = a;
    }
    u16* dst = (eg < 4) ? q : (eg < 8) ? k : v;
    const int d0 = (eg & 3) * 16;
    unsigned int p[8];
#pragma unroll
    for (int t = 0; t < 8; ++t)
      p[t] = (unsigned int)f2bf(acc[2*t]) | ((unsigned int)f2bf(acc[2*t+1]) << 16);
    uint4* dp = (uint4*)(dst + obase + d0);
    dp[0] = make_uint4(p[0], p[1], p[2], p[3]);
    dp[1] = make_uint4(p[4], p[5], p[6], p[7]);
  }
}

// ---------------------------------------------------------------------------
// R23 MFMA flash attention. R17 body + XCD-chunked swizzle: flatten bid,
// wid=(bid&7)*128+(bid>>3) -> each XCD serves 8 complete (h,z) KV panels
// (4MB = one L2). Block i owns strips i (u0) and 31-i (u1), uniform 33
// tile-units/wave. Swapped QK^T; fixed-ref softmax p=exp2(s); cvt_pk pack.
// ---------------------------------------------------------------------------
__global__ __launch_bounds__(256, 4) void attn_mfma_kernel(
    const u16* __restrict__ q, const u16* __restrict__ k,
    const u16* __restrict__ v, u16* __restrict__ o)
{
  const int bid = blockIdx.x + (blockIdx.y << 4) + (blockIdx.z << 8);  // 0..1023
  const int wid = ((bid & 7) << 7) + (bid >> 3);   // XCD-chunked, bijective
  const int bi  = wid & 15;            // strip pair index 0..15
  const int h   = (wid >> 4) & 15;
  const int z   = wid >> 8;
  const int qb0 = bi * 64;             // top subtile (u=0)
  const int qb1 = (31 - bi) * 64;      // bottom subtile (u=1)
  const int tid = threadIdx.x;
  const int w = tid >> 6, lane = tid & 63;
  const int col = lane & 15, quad = lane >> 4;

  __shared__ __align__(16) u16 Ks[64 * 72];
  __shared__ __align__(16) u16 Vt[64 * 72];
  __shared__ __align__(16) u16 Ps[4][16 * 72];

  const size_t hs = ((size_t)z * H_ + h) * S_ * HS_;

  // Q fragments for the two subtiles; scale folds 1/8 and log2(e).
  const float qs = 0.125f * 1.44269504089f;
  bf16x8 qf[2][2];
#pragma unroll
  for (int u = 0; u < 2; ++u) {
    const int qb = u ? qb1 : qb0;
    const u16* qp = q + hs + (size_t)(qb + w * 16 + col) * HS_ + quad * 8;
#pragma unroll
    for (int ks = 0; ks < 2; ++ks) {
      u16 t8[8];
      *(uint4*)t8 = *(const uint4*)(qp + ks * 32);
#pragma unroll
      for (int e = 0; e < 8; ++e) t8[e] = f2bf(bf2f(t8[e]) * qs);
      qf[u][ks] = *(bf16x8*)t8;
    }
  }

  const int sr = tid >> 2, sc = (tid & 3) * 16;        // K staging: 64x64
  const int vr = (tid & 31) * 2, vc = (tid >> 5) * 8;  // V staging: 2 rows x 8 cols

  f32x4 oacc[2][4] = {};
  float l_run[2] = {0.f, 0.f};         // per-lane PARTIAL row sums

  const int jbmax = qb1;               // bottom subtile's diagonal tile

  // prologue: load tile 0
  uint4 k0, k1, va, vb;
  {
    const u16* kp = k + hs + (size_t)sr * HS_ + sc;
    k0 = *(const uint4*)kp;
    k1 = *(const uint4*)(kp + 8);
    const u16* vp = v + hs + (size_t)vr * HS_ + vc;
    va = *(const uint4*)vp;
    vb = *(const uint4*)(vp + HS_);
  }

  for (int jb = 0; jb <= jbmax; jb += 64) {
    __syncthreads();                       // all waves done reading prev tile
    *(uint4*)(Ks + sr * 72 + sc)     = k0;
    *(uint4*)(Ks + sr * 72 + sc + 8) = k1;
    {
      const u16* pa = (const u16*)&va;
      const u16* pb = (const u16*)&vb;
#pragma unroll
      for (int e = 0; e < 8; ++e)
        *(unsigned int*)(Vt + (vc + e) * 72 + vr) =
            (unsigned int)pa[e] | ((unsigned int)pb[e] << 16);
    }
    __syncthreads();

    if (jb < jbmax) {                      // prefetch next tile under compute
      const u16* kp = k + hs + (size_t)(jb + 64 + sr) * HS_ + sc;
      k0 = *(const uint4*)kp;
      k1 = *(const uint4*)(kp + 8);
      const u16* vp = v + hs + (size_t)(jb + 64 + vr) * HS_ + vc;
      va = *(const uint4*)vp;
      vb = *(const uint4*)(vp + HS_);
    }

#pragma unroll
    for (int u = 0; u < 2; ++u) {
      const int ru = (u ? qb1 : qb0) + w * 16;
      if (jb > ru + 15) continue;          // subtile fully above diagonal

      // Swapped QK^T: D[k-row = quad*4+r][q-col = col]
      f32x4 sacc[4] = {};
      __builtin_amdgcn_s_setprio(1);
#pragma unroll
      for (int ks = 0; ks < 2; ++ks)
#pragma unroll
        for (int t = 0; t < 4; ++t) {
          const bf16x8 kf = *(const bf16x8*)(Ks + (t * 16 + col) * 72 + ks * 32 + quad * 8);
          sacc[t] = __builtin_amdgcn_mfma_f32_16x16x32_bf16(kf, qf[u][ks], sacc[t], 0, 0, 0);
        }
      __builtin_amdgcn_s_setprio(0);

      if (jb + 63 > ru) {                  // diagonal tile: mask k > q
        const int q_l = ru + col;
#pragma unroll
        for (int t = 0; t < 4; ++t) {
          const int kb = jb + t * 16 + quad * 4;
#pragma unroll
          for (int r = 0; r < 4; ++r)
            if (kb + r > q_l) sacc[t][r] = -INFINITY;
        }
      }

      // Fixed-reference softmax: p = exp2(s) directly (|s| <~ 16; safe).
      float ls = 0.f;
#pragma unroll
      for (int t = 0; t < 4; ++t) {
        const float p0 = __builtin_amdgcn_exp2f(sacc[t][0]);
        const float p1 = __builtin_amdgcn_exp2f(sacc[t][1]);
        const float p2 = __builtin_amdgcn_exp2f(sacc[t][2]);
        const float p3 = __builtin_amdgcn_exp2f(sacc[t][3]);
        ls += (p0 + p1) + (p2 + p3);
        *(uint2*)(Ps[w] + col * 72 + t * 16 + quad * 4) =
            make_uint2(cvtpk(p0, p1), cvtpk(p2, p3));
      }
      l_run[u] += ls;

      __builtin_amdgcn_s_setprio(1);
#pragma unroll
      for (int ks = 0; ks < 2; ++ks) {
        const bf16x8 pf = *(const bf16x8*)(Ps[w] + col * 72 + ks * 32 + quad * 8);
#pragma unroll
        for (int nt = 0; nt < 4; ++nt) {
          const bf16x8 vf = *(const bf16x8*)(Vt + (nt * 16 + col) * 72 + ks * 32 + quad * 8);
          oacc[u][nt] = __builtin_amdgcn_mfma_f32_16x16x32_bf16(pf, vf, oacc[u][nt], 0, 0, 0);
        }
      }
      __builtin_amdgcn_s_setprio(0);
    }
  }

  u16* ob = o + (size_t)z * S_ * V_ + h * HS_;
#pragma unroll
  for (int u = 0; u < 2; ++u) {
    const int ru = (u ? qb1 : qb0) + w * 16;
    float lt = l_run[u];                   // reduce partials once
    lt += __shfl_xor(lt, 16);
    lt += __shfl_xor(lt, 32);
    float inv[4];
#pragma unroll
    for (int r = 0; r < 4; ++r) inv[r] = 1.0f / __shfl(lt, quad * 4 + r);
#pragma unroll
    for (int nt = 0; nt < 4; ++nt)
#pragma unroll
      for (int r = 0; r < 4; ++r)
        ob[(size_t)(ru + quad * 4 + r) * V_ + nt * 16 + col] = f2bf(oacc[u][nt][r] * inv[r]);
  }
}

// ---------------------------------------------------------------------------
// Output projection, MFMA NT-GEMM (R22). 512 threads / 8 waves, tile
// 128x128, BK=64, reg-prefetch. Wave w owns 64x32 quadrant.
// ---------------------------------------------------------------------------
__global__ __launch_bounds__(512) void oproj_mfma_kernel(
    const u16* __restrict__ a, const u16* __restrict__ bw, float* __restrict__ c)
{
  __shared__ __align__(16) u16 As[128 * 72];
  __shared__ __align__(16) u16 Bs[128 * 72];
  const int tid = threadIdx.x;        // 0..511
  const int m0 = blockIdx.x * 128;
  const int n0 = blockIdx.y * 128;
  const int w = tid >> 6, lane = tid & 63;
  const int col = lane & 15, quad = lane >> 4;
  const int qr = (w & 1) * 64;        // row half
  const int qc = (w >> 1) * 32;       // col strip

  f32x4 acc[4][2] = {};

  const int sr = tid >> 2;            // 0..127 (all rows)
  const int sk = (tid & 3) * 16;      // 0,16,32,48 (u16 units)
  const u16* ga = a  + (size_t)(m0 + sr) * GK_ + sk;
  const u16* gb = bw + (size_t)(n0 + sr) * GK_ + sk;

  // prologue: stage k0 = 0 (2 uint4 per matrix per thread)
  uint4 a0 = *(const uint4*)(ga);
  uint4 a1 = *(const uint4*)(ga + 8);
  uint4 b0 = *(const uint4*)(gb);
  uint4 b1 = *(const uint4*)(gb + 8);

  for (int k0 = 0; k0 < GK_; k0 += 64) {
    __syncthreads();                       // prev tile reads done
    *(uint4*)(As + sr * 72 + sk)     = a0;
    *(uint4*)(As + sr * 72 + sk + 8) = a1;
    *(uint4*)(Bs + sr * 72 + sk)     = b0;
    *(uint4*)(Bs + sr * 72 + sk + 8) = b1;
    __syncthreads();

    if (k0 + 64 < GK_) {                   // prefetch k+64 under compute
      a0 = *(const uint4*)(ga + k0 + 64);
      a1 = *(const uint4*)(ga + k0 + 64 + 8);
      b0 = *(const uint4*)(gb + k0 + 64);
      b1 = *(const uint4*)(gb + k0 + 64 + 8);
    }

#pragma unroll
    for (int ks = 0; ks < 2; ++ks) {
      bf16x8 af[4], bfr[2];
#pragma unroll
      for (int i = 0; i < 4; ++i)
        af[i] = *(const bf16x8*)(As + (qr + i * 16 + col) * 72 + ks * 32 + quad * 8);
#pragma unroll
      for (int j = 0; j < 2; ++j)
        bfr[j] = *(const bf16x8*)(Bs + (qc + j * 16 + col) * 72 + ks * 32 + quad * 8);
      __builtin_amdgcn_s_setprio(1);
#pragma unroll
      for (int i = 0; i < 4; ++i)
#pragma unroll
        for (int j = 0; j < 2; ++j)
          acc[i][j] = __builtin_amdgcn_mfma_f32_16x16x32_bf16(af[i], bfr[j], acc[i][j], 0, 0, 0);
      __builtin_amdgcn_s_setprio(0);
    }
  }

#pragma unroll
  for (int i = 0; i < 4; ++i)
#pragma unroll
    for (int j = 0; j < 2; ++j)
#pragma unroll
      for (int r = 0; r < 4; ++r)
        c[(size_t)(m0 + qr + i * 16 + quad * 4 + r) * GN_ + n0 + qc + j * 16 + col]
            = acc[i][j][r];
}

// ---------------------------------------------------------------------------
// Fallback vector oproj (per-batch mode only; unchanged).
// ---------------------------------------------------------------------------
__global__ __launch_bounds__(256) void oproj_vec_kernel(
    const u16* __restrict__ o, const void* __restrict__ w,
    float* __restrict__ out, const int* __restrict__ flag)
{
  __shared__ __align__(16) float At[64 * 68];
  __shared__ __align__(16) float Wt[64 * 68];
  const int tid = threadIdx.x;
  const size_t zo = (size_t)blockIdx.z * S_ * V_;
  const int m0 = blockIdx.x * 64;
  const int n0 = blockIdx.y * 64;
  const int tr = tid >> 4, tc = tid & 15;
  const int isf32 = *flag;
  const int srow = tid >> 2, sc = (tid & 3) * 16;

  float acc[4][4] = {};

  for (int k0 = 0; k0 < GK_; k0 += 64) {
    float av[16], wv[16];
    {
      const u16* gp = o + zo + (size_t)(m0 + srow) * GK_ + k0 + sc;
      uint4 u0 = *(const uint4*)gp;
      uint4 u1 = *(const uint4*)(gp + 8);
      av[0]=lo16(u0.x); av[1]=hi16(u0.x); av[2]=lo16(u0.y); av[3]=hi16(u0.y);
      av[4]=lo16(u0.z); av[5]=hi16(u0.z); av[6]=lo16(u0.w); av[7]=hi16(u0.w);
      av[8]=lo16(u1.x); av[9]=hi16(u1.x); av[10]=lo16(u1.y); av[11]=hi16(u1.y);
      av[12]=lo16(u1.z); av[13]=hi16(u1.z); av[14]=lo16(u1.w); av[15]=hi16(u1.w);
    }
    if (isf32) {
      const float4* gp = (const float4*)((const float*)w + (size_t)(n0 + srow) * GK_ + k0 + sc);
#pragma unroll
      for (int i = 0; i < 4; ++i) {
        float4 f = gp[i];
        wv[4*i+0]=f.x; wv[4*i+1]=f.y; wv[4*i+2]=f.z; wv[4*i+3]=f.w;
      }
    } else {
      const u16* gp = (const u16*)w + (size_t)(n0 + srow) * GK_ + k0 + sc;
      uint4 u0 = *(const uint4*)gp;
      uint4 u1 = *(const uint4*)(gp + 8);
      wv[0]=lo16(u0.x); wv[1]=hi16(u0.x); wv[2]=lo16(u0.y); wv[3]=hi16(u0.y);
      wv[4]=lo16(u0.z); wv[5]=hi16(u0.z); wv[6]=lo16(u0.w); wv[7]=hi16(u0.w);
      wv[8]=lo16(u1.x); wv[9]=hi16(u1.x); wv[10]=lo16(u1.y); wv[11]=hi16(u1.y);
      wv[12]=lo16(u1.z); wv[13]=hi16(u1.z); wv[14]=lo16(u1.w); wv[15]=hi16(u1.w);
    }
    __syncthreads();
#pragma unroll
    for (int i = 0; i < 16; ++i) {
      At[(sc + i) * 68 + srow] = av[i];
      Wt[(sc + i) * 68 + srow] = wv[i];
    }
    __syncthreads();

#pragma unroll 4
    for (int kk = 0; kk < 64; ++kk) {
      float4 a4 = *(const float4*)&At[kk * 68 + tr * 4];
      float4 w4 = *(const float4*)&Wt[kk * 68 + tc * 4];
      acc[0][0] += a4.x*w4.x; acc[0][1] += a4.x*w4.y; acc[0][2] += a4.x*w4.z; acc[0][3] += a4.x*w4.w;
      acc[1][0] += a4.y*w4.x; acc[1][1] += a4.y*w4.y; acc[1][2] += a4.y*w4.z; acc[1][3] += a4.y*w4.w;
      acc[2][0] += a4.z*w4.x; acc[2][1] += a4.z*w4.y; acc[2][2] += a4.z*w4.z; acc[2][3] += a4.z*w4.w;
      acc[3][0] += a4.w*w4.x; acc[3][1] += a4.w*w4.y; acc[3][2] += a4.w*w4.z; acc[3][3] += a4.w*w4.w;
    }
  }

#pragma unroll
  for (int r = 0; r < 4; ++r) {
    const int row = m0 + tr * 4 + r;
    *(float4*)(out + zo + (size_t)row * GN_ + n0 + tc * 4) =
        make_float4(acc[r][0], acc[r][1], acc[r][2], acc[r][3]);
  }
}

// ---------------------------------------------------------------------------
extern "C" void kernel_launch(void* const* d_in, const int* in_sizes, int n_in,
                              void* d_out, int out_size, void* d_ws, size_t ws_size,
                              hipStream_t stream) {
  const void* x = d_in[0];
  const void* wqkv = (n_in > 1) ? d_in[1] : d_in[0];
  const void* wout = (n_in > 2) ? d_in[2] : d_in[0];
  for (int i = 0; i < n_in; ++i) {
    if      (in_sizes[i] == B_ * S_ * V_)  x    = d_in[i];
    else if (in_sizes[i] == 3 * HS_ * HS_) wqkv = d_in[i];
    else if (in_sizes[i] == V_ * V_)       wout = d_in[i];
  }
  float* out = (float*)d_out;

  const size_t per_b = (size_t)H_ * S_ * HS_;
  const size_t SV = (size_t)S_ * V_;
  int* flag = (int*)d_ws;
  const bool full = ws_size >= (16 + 16 * per_b * sizeof(u16));
  const size_t stride = full ? 4 * per_b : per_b;
  u16* q = (u16*)((char*)d_ws + 16);
  u16* k = q + stride;
  u16* v = k + stride;
  u16* o = v + stride;

  detect_kernel<<<dim3(1), dim3(256), 0, stream>>>((const unsigned int*)x, flag);
  if (full) {
    qkv_mfma_kernel<<<dim3((B_ * S_ * H_) / 128), dim3(256), 0, stream>>>(
        x, wqkv, q, k, v, flag);
    attn_mfma_kernel<<<dim3(16, 16, B_), dim3(256), 0, stream>>>(q, k, v, o);
    u16* wb = q;   // q dead after attn
    wcvt_kernel<<<dim3((V_ * V_) / 1024), dim3(256), 0, stream>>>(wout, wb, flag);
    oproj_mfma_kernel<<<dim3((B_ * S_) / 128, GN_ / 128), dim3(512), 0, stream>>>(o, wb, out);
  } else {
    for (int b = 0; b < B_; ++b) {
      qkv_kernel<<<dim3(128, 1, 1), dim3(256), 0, stream>>>(x, b, wqkv, q, k, v, flag);
      attn_mfma_kernel<<<dim3(16, 16, 1), dim3(256), 0, stream>>>(q, k, v, o);
      oproj_vec_kernel<<<dim3(32, 16, 1), dim3(256), 0, stream>>>(
          o, wout, out + (size_t)b * SV, flag);
    }
  }
}